// Round 1
// baseline (601.791 us; speedup 1.0000x reference)
//
#include <hip/hip_runtime.h>
#include <math.h>

// Problem constants (from setup_inputs)
#define CDIM 2048
#define HF 24
#define WF 24
#define PIX 576      // HF*WF
#define HO 18
#define WO 18
#define NP 324       // HO*WO patches
#define NHEAD 32
#define HD 64
#define NTOK 50      // 1 mean + 49
#define NTXT 45
#define OUTD 512
#define NKV 626      // 576 pixel cols + 50 pos cols
#define NQ 325       // 324 meanfeat cols + 1 pos0 col

// ---------------------------------------------------------------------------
// Kernel 1: meanfeat[c][p] = mean over 7x7 window of feat1[c][.]
__global__ void meanfeat_k(const float* __restrict__ feat1, float* __restrict__ mf) {
    int g = blockIdx.x * 256 + threadIdx.x;
    if (g >= CDIM * NP) return;
    int c = g / NP, p = g % NP;
    int i = p / WO, j = p % WO;
    const float* base = feat1 + (size_t)c * PIX + i * WF + j;
    float s = 0.f;
#pragma unroll
    for (int di = 0; di < 7; ++di)
#pragma unroll
        for (int dj = 0; dj < 7; ++dj)
            s += base[di * WF + dj];
    mf[c * NP + p] = s * (1.f / 49.f);
}

// ---------------------------------------------------------------------------
// Kernel 2: fused triple GEMM.  out[n][o] = sum_c W[o][c] * X[c][n] (+bias for n>=bias_start)
// z=0: K: X = [feat1(576) | pos^T(50)], z=1: V same, z=2: Q: X = [meanfeat(324) | pos0(1)]
__global__ __launch_bounds__(256) void gemm_k(
    const float* __restrict__ k_w, const float* __restrict__ v_w, const float* __restrict__ q_w,
    const float* __restrict__ feat1, const float* __restrict__ mf, const float* __restrict__ pos,
    const float* __restrict__ k_b, const float* __restrict__ v_b, const float* __restrict__ q_b,
    float* __restrict__ Kbuf, float* __restrict__ Vbuf, float* __restrict__ Qbuf)
{
    const float* W; const float* X1; const float* bias; float* out;
    int ld1, split, Ntot;
    int z = blockIdx.z;
    if (z == 0)      { W = k_w; X1 = feat1; ld1 = PIX; split = PIX; Ntot = NKV; bias = k_b; out = Kbuf; }
    else if (z == 1) { W = v_w; X1 = feat1; ld1 = PIX; split = PIX; Ntot = NKV; bias = v_b; out = Vbuf; }
    else             { W = q_w; X1 = mf;    ld1 = NP;  split = NP;  Ntot = NQ;  bias = q_b; out = Qbuf; }
    int bias_start = split;

    int m0 = blockIdx.x * 64;
    int n0 = blockIdx.y * 64;
    if (n0 >= Ntot) return;

    __shared__ float Ws[16][68];  // [kk][mm]
    __shared__ float Xs[16][68];  // [kk][nn]
    int tid = threadIdx.x;
    int tx = tid & 15, ty = tid >> 4;

    float acc[4][4] = {};

    for (int k0 = 0; k0 < CDIM; k0 += 16) {
        // stage W tile: 64 m-rows x 16 k-cols
        {
            int row = tid >> 2;
            int cg = (tid & 3) * 4;
            float4 wv = *(const float4*)(W + (size_t)(m0 + row) * CDIM + k0 + cg);
            Ws[cg + 0][row] = wv.x; Ws[cg + 1][row] = wv.y;
            Ws[cg + 2][row] = wv.z; Ws[cg + 3][row] = wv.w;
        }
        // stage X tile: 16 k-rows x 64 n-cols
        {
            int kk = tid >> 4;
            int nn = (tid & 15) * 4;
            int cg = k0 + kk;
#pragma unroll
            for (int u = 0; u < 4; ++u) {
                int n = n0 + nn + u;
                float vv = 0.f;
                if (n < split)      vv = X1[(size_t)cg * ld1 + n];
                else if (n < Ntot)  vv = pos[(size_t)(n - split) * CDIM + cg];
                Xs[kk][nn + u] = vv;
            }
        }
        __syncthreads();
#pragma unroll
        for (int kk = 0; kk < 16; ++kk) {
            float4 av = *(const float4*)&Ws[kk][ty * 4];
            float4 bv = *(const float4*)&Xs[kk][tx * 4];
            float a[4] = {av.x, av.y, av.z, av.w};
            float b[4] = {bv.x, bv.y, bv.z, bv.w};
#pragma unroll
            for (int mi = 0; mi < 4; ++mi)
#pragma unroll
                for (int ni = 0; ni < 4; ++ni)
                    acc[mi][ni] += a[mi] * b[ni];
        }
        __syncthreads();
    }

    float4 bv4 = *(const float4*)(bias + m0 + ty * 4);
    float bvals[4] = {bv4.x, bv4.y, bv4.z, bv4.w};
#pragma unroll
    for (int ni = 0; ni < 4; ++ni) {
        int n = n0 + tx * 4 + ni;
        if (n >= Ntot) continue;
        float4 r;
        r.x = acc[0][ni]; r.y = acc[1][ni]; r.z = acc[2][ni]; r.w = acc[3][ni];
        if (n >= bias_start) { r.x += bvals[0]; r.y += bvals[1]; r.z += bvals[2]; r.w += bvals[3]; }
        *(float4*)(out + (size_t)n * CDIM + m0 + ty * 4) = r;
    }
}

// ---------------------------------------------------------------------------
// Kernel 3: per-patch window means of Kf/Vf (pure mean, no pos/bias)
__global__ __launch_bounds__(256) void meanskv_k(const float* __restrict__ Kbuf, const float* __restrict__ Vbuf,
                                                 float* __restrict__ kmean, float* __restrict__ vmean) {
    int p = blockIdx.x;
    int i = p / WO, j = p % WO;
    int tid = threadIdx.x;
    float sk[8] = {}, sv[8] = {};
    for (int t = 0; t < 49; ++t) {
        int pix = (i + t / 7) * WF + (j + t % 7);
        const float* kr = Kbuf + (size_t)pix * CDIM;
        const float* vr = Vbuf + (size_t)pix * CDIM;
#pragma unroll
        for (int r = 0; r < 8; ++r) {
            int c = tid + 256 * r;
            sk[r] += kr[c];
            sv[r] += vr[c];
        }
    }
#pragma unroll
    for (int r = 0; r < 8; ++r) {
        int c = tid + 256 * r;
        kmean[(size_t)p * CDIM + c] = sk[r] * (1.f / 49.f);
        vmean[(size_t)p * CDIM + c] = sv[r] * (1.f / 49.f);
    }
}

// ---------------------------------------------------------------------------
// Kernel 4: per-patch attention + out-proj + text argmax -> bucket
__global__ __launch_bounds__(256) void attn_k(
    const float* __restrict__ Kbuf, const float* __restrict__ Vbuf, const float* __restrict__ Qbuf,
    const float* __restrict__ kmean, const float* __restrict__ vmean,
    const float* __restrict__ out_w, const float* __restrict__ out_b,
    const float* __restrict__ txt, int* __restrict__ bucket)
{
    __shared__ float qs[CDIM];
    __shared__ float sc[NHEAD][NTOK];
    __shared__ float pooled[CDIM];
    __shared__ float ov[OUTD];
    __shared__ float sv[48];

    int p = blockIdx.x;
    int pi = p / WO, pj = p % WO;
    int tid = threadIdx.x;

    // q = Qm[p] + Qp0
#pragma unroll
    for (int r = 0; r < 8; ++r) {
        int c = tid + 256 * r;
        qs[c] = Qbuf[(size_t)p * CDIM + c] + Qbuf[(size_t)NP * CDIM + c];
    }
    __syncthreads();

    // scores: 32 heads x 50 tokens
    for (int pair = tid; pair < NHEAD * NTOK; pair += 256) {
        int h = pair / NTOK, t = pair % NTOK;
        const float* kb = (t == 0) ? (kmean + (size_t)p * CDIM)
                                   : (Kbuf + (size_t)((pi + (t - 1) / 7) * WF + pj + (t - 1) % 7) * CDIM);
        const float* kp = Kbuf + (size_t)(PIX + t) * CDIM;
        int base = h * HD;
        float dot = 0.f;
#pragma unroll
        for (int d = 0; d < HD; d += 4) {
            float4 qv = *(const float4*)&qs[base + d];
            float4 kv = *(const float4*)&kb[base + d];
            float4 pv = *(const float4*)&kp[base + d];
            dot += qv.x * (kv.x + pv.x) + qv.y * (kv.y + pv.y)
                 + qv.z * (kv.z + pv.z) + qv.w * (kv.w + pv.w);
        }
        sc[h][t] = dot * 0.125f;  // 1/sqrt(64)
    }
    __syncthreads();

    // softmax per head
    if (tid < NHEAD) {
        int h = tid;
        float m = -1e30f;
        for (int t = 0; t < NTOK; ++t) m = fmaxf(m, sc[h][t]);
        float s = 0.f;
        for (int t = 0; t < NTOK; ++t) { float e = expf(sc[h][t] - m); sc[h][t] = e; s += e; }
        float inv = 1.f / s;
        for (int t = 0; t < NTOK; ++t) sc[h][t] *= inv;
    }
    __syncthreads();

    // pooled = attn @ v
    {
        float accv[8] = {};
        for (int t = 0; t < NTOK; ++t) {
            const float* vb = (t == 0) ? (vmean + (size_t)p * CDIM)
                                       : (Vbuf + (size_t)((pi + (t - 1) / 7) * WF + pj + (t - 1) % 7) * CDIM);
            const float* vp = Vbuf + (size_t)(PIX + t) * CDIM;
#pragma unroll
            for (int r = 0; r < 8; ++r) {
                int c = tid + 256 * r;
                float a = sc[c >> 6][t];
                accv[r] += a * (vb[c] + vp[c]);
            }
        }
#pragma unroll
        for (int r = 0; r < 8; ++r) pooled[tid + 256 * r] = accv[r];
    }
    __syncthreads();

    // out projection (512 outputs)
#pragma unroll
    for (int rr = 0; rr < 2; ++rr) {
        int o = tid + rr * 256;
        const float* wrow = out_w + (size_t)o * CDIM;
        float acc = out_b[o];
        for (int cc = 0; cc < CDIM; cc += 4) {
            float4 wv = *(const float4*)&wrow[cc];
            float4 pv = *(const float4*)&pooled[cc];
            acc += wv.x * pv.x + wv.y * pv.y + wv.z * pv.z + wv.w * pv.w;
        }
        ov[o] = acc;
    }
    __syncthreads();

    // text scores (normalization of pooled cancels in argmax; txt normalized per row)
    if (tid < NTXT) {
        const float* tr = txt + (size_t)tid * OUTD;
        float dot = 0.f, n2 = 0.f;
        for (int o2 = 0; o2 < OUTD; o2 += 4) {
            float4 tv = *(const float4*)&tr[o2];
            float4 vv = *(const float4*)&ov[o2];
            dot += tv.x * vv.x + tv.y * vv.y + tv.z * vv.z + tv.w * vv.w;
            n2  += tv.x * tv.x + tv.y * tv.y + tv.z * tv.z + tv.w * tv.w;
        }
        sv[tid] = dot / sqrtf(n2);
    }
    __syncthreads();

    if (tid == 0) {
        float best = sv[0]; int bi = 0;
        for (int j2 = 1; j2 < NTXT; ++j2)
            if (sv[j2] > best) { best = sv[j2]; bi = j2; }
        int bk = 0;
        const int bounds[5] = {8, 15, 22, 29, 36};
#pragma unroll
        for (int u = 0; u < 5; ++u) bk += (bi >= bounds[u]) ? 1 : 0;
        bucket[p] = bk;
    }
}

// ---------------------------------------------------------------------------
// Kernel 5: vote conv (7x7 ones, full padding) + channel argmax -> binary map value
__global__ void votes_k(const int* __restrict__ bucket, float* __restrict__ maxval) {
    __shared__ int bk[NP];
    int tid = threadIdx.x;
    if (tid < NP) bk[tid] = bucket[tid];
    __syncthreads();
    if (tid < PIX) {
        int y = tid / WF, x = tid % WF;
        int cnt[6] = {0, 0, 0, 0, 0, 0};
        int i0 = (y - 6 < 0) ? 0 : y - 6;
        int i1 = (y > HO - 1) ? HO - 1 : y;
        int j0 = (x - 6 < 0) ? 0 : x - 6;
        int j1 = (x > WO - 1) ? WO - 1 : x;
        for (int i = i0; i <= i1; ++i)
            for (int j = j0; j <= j1; ++j)
                cnt[bk[i * WO + j]]++;
        int best = cnt[0], bi = 0;
#pragma unroll
        for (int ch = 1; ch < 6; ++ch)
            if (cnt[ch] > best) { best = cnt[ch]; bi = ch; }
        maxval[tid] = (bi > 0) ? 0.044194173824159216f : 0.f;  // 1/sqrt(512)
    }
}

// ---------------------------------------------------------------------------
// Kernel 6: fill output (batch 0 = 0, batch 1 = maxval broadcast over 512 ch)
__global__ void fill_k(const float* __restrict__ maxval, float* __restrict__ out) {
    int idx = blockIdx.x * 256 + threadIdx.x;
    const int HALF = OUTD * PIX;  // 294912
    if (idx >= 2 * HALF) return;
    out[idx] = (idx < HALF) ? 0.f : maxval[idx % PIX];
}

// ---------------------------------------------------------------------------
extern "C" void kernel_launch(void* const* d_in, const int* in_sizes, int n_in,
                              void* d_out, int out_size, void* d_ws, size_t ws_size,
                              hipStream_t stream) {
    const float* imgf = (const float*)d_in[0];
    const float* txt  = (const float*)d_in[1];
    const float* pos  = (const float*)d_in[2];
    const float* q_w  = (const float*)d_in[3];
    const float* q_b  = (const float*)d_in[4];
    const float* k_w  = (const float*)d_in[5];
    const float* k_b  = (const float*)d_in[6];
    const float* v_w  = (const float*)d_in[7];
    const float* v_b  = (const float*)d_in[8];
    const float* o_w  = (const float*)d_in[9];
    const float* o_b  = (const float*)d_in[10];

    const float* feat1 = imgf + (size_t)1 * CDIM * PIX;  // only batch B-1=1 matters

    float* ws = (float*)d_ws;
    float* Kbuf  = ws;                        // 626*2048
    float* Vbuf  = Kbuf + (size_t)NKV * CDIM; // 626*2048
    float* Qbuf  = Vbuf + (size_t)NKV * CDIM; // 325*2048
    float* mf    = Qbuf + (size_t)NQ * CDIM;  // 2048*324
    float* kmean = mf + (size_t)CDIM * NP;    // 324*2048
    float* vmean = kmean + (size_t)NP * CDIM; // 324*2048
    int*   bucket = (int*)(vmean + (size_t)NP * CDIM);
    float* maxval = (float*)(bucket + NP);

    meanfeat_k<<<dim3((CDIM * NP + 255) / 256), dim3(256), 0, stream>>>(feat1, mf);
    gemm_k<<<dim3(CDIM / 64, (NKV + 63) / 64, 3), dim3(256), 0, stream>>>(
        k_w, v_w, q_w, feat1, mf, pos, k_b, v_b, q_b, Kbuf, Vbuf, Qbuf);
    meanskv_k<<<dim3(NP), dim3(256), 0, stream>>>(Kbuf, Vbuf, kmean, vmean);
    attn_k<<<dim3(NP), dim3(256), 0, stream>>>(Kbuf, Vbuf, Qbuf, kmean, vmean, o_w, o_b, txt, bucket);
    votes_k<<<dim3(1), dim3(576), 0, stream>>>(bucket, maxval);
    fill_k<<<dim3((2 * OUTD * PIX + 255) / 256), dim3(256), 0, stream>>>(maxval, (float*)d_out);
}

// Round 2
// 448.807 us; speedup vs baseline: 1.3409x; 1.3409x over previous
//
#include <hip/hip_runtime.h>
#include <math.h>

// Problem constants (from setup_inputs)
#define CDIM 2048
#define HF 24
#define WF 24
#define PIX 576      // HF*WF
#define HO 18
#define WO 18
#define NP 324       // HO*WO patches
#define NHEAD 32
#define HD 64
#define NTOK 50      // 1 mean + 49
#define NTXT 45
#define OUTD 512
#define NKV 626      // 576 pixel cols + 50 pos cols
#define NQ 325       // 324 meanfeat cols + 1 pos0 col
#define HJ (NHEAD * NTXT)   // 1440: (head, txt) pairs per column

// ---------------------------------------------------------------------------
// Kernel 1: meanfeat[c][p] = mean over 7x7 window of feat1[c][.]
__global__ void meanfeat_k(const float* __restrict__ feat1, float* __restrict__ mf) {
    int g = blockIdx.x * 256 + threadIdx.x;
    if (g >= CDIM * NP) return;
    int c = g / NP, p = g % NP;
    int i = p / WO, j = p % WO;
    const float* base = feat1 + (size_t)c * PIX + i * WF + j;
    float s = 0.f;
#pragma unroll
    for (int di = 0; di < 7; ++di)
#pragma unroll
        for (int dj = 0; dj < 7; ++dj)
            s += base[di * WF + dj];
    mf[c * NP + p] = s * (1.f / 49.f);
}

// ---------------------------------------------------------------------------
// Kernel 2: fused triple GEMM.  out[n][o] = sum_c W[o][c] * X[c][n] (+bias for n>=bias_start)
// z=0: K: X = [feat1(576) | pos^T(50)], z=1: V same, z=2: Q: X = [meanfeat(324) | pos0(1)]
__global__ __launch_bounds__(256) void gemm_k(
    const float* __restrict__ k_w, const float* __restrict__ v_w, const float* __restrict__ q_w,
    const float* __restrict__ feat1, const float* __restrict__ mf, const float* __restrict__ pos,
    const float* __restrict__ k_b, const float* __restrict__ v_b, const float* __restrict__ q_b,
    float* __restrict__ Kbuf, float* __restrict__ Vbuf, float* __restrict__ Qbuf)
{
    const float* W; const float* X1; const float* bias; float* out;
    int ld1, split, Ntot;
    int z = blockIdx.z;
    if (z == 0)      { W = k_w; X1 = feat1; ld1 = PIX; split = PIX; Ntot = NKV; bias = k_b; out = Kbuf; }
    else if (z == 1) { W = v_w; X1 = feat1; ld1 = PIX; split = PIX; Ntot = NKV; bias = v_b; out = Vbuf; }
    else             { W = q_w; X1 = mf;    ld1 = NP;  split = NP;  Ntot = NQ;  bias = q_b; out = Qbuf; }
    int bias_start = split;

    int m0 = blockIdx.x * 64;
    int n0 = blockIdx.y * 64;
    if (n0 >= Ntot) return;

    __shared__ float Ws[16][68];  // [kk][mm]
    __shared__ float Xs[16][68];  // [kk][nn]
    int tid = threadIdx.x;
    int tx = tid & 15, ty = tid >> 4;

    float acc[4][4] = {};

    for (int k0 = 0; k0 < CDIM; k0 += 16) {
        // stage W tile: 64 m-rows x 16 k-cols
        {
            int row = tid >> 2;
            int cg = (tid & 3) * 4;
            float4 wv = *(const float4*)(W + (size_t)(m0 + row) * CDIM + k0 + cg);
            Ws[cg + 0][row] = wv.x; Ws[cg + 1][row] = wv.y;
            Ws[cg + 2][row] = wv.z; Ws[cg + 3][row] = wv.w;
        }
        // stage X tile: 16 k-rows x 64 n-cols
        {
            int kk = tid >> 4;
            int nn = (tid & 15) * 4;
            int cg = k0 + kk;
#pragma unroll
            for (int u = 0; u < 4; ++u) {
                int n = n0 + nn + u;
                float vv = 0.f;
                if (n < split)      vv = X1[(size_t)cg * ld1 + n];
                else if (n < Ntot)  vv = pos[(size_t)(n - split) * CDIM + cg];
                Xs[kk][nn + u] = vv;
            }
        }
        __syncthreads();
#pragma unroll
        for (int kk = 0; kk < 16; ++kk) {
            float4 av = *(const float4*)&Ws[kk][ty * 4];
            float4 bv = *(const float4*)&Xs[kk][tx * 4];
            float a[4] = {av.x, av.y, av.z, av.w};
            float b[4] = {bv.x, bv.y, bv.z, bv.w};
#pragma unroll
            for (int mi = 0; mi < 4; ++mi)
#pragma unroll
                for (int ni = 0; ni < 4; ++ni)
                    acc[mi][ni] += a[mi] * b[ni];
        }
        __syncthreads();
    }

    float4 bv4 = *(const float4*)(bias + m0 + ty * 4);
    float bvals[4] = {bv4.x, bv4.y, bv4.z, bv4.w};
#pragma unroll
    for (int ni = 0; ni < 4; ++ni) {
        int n = n0 + tx * 4 + ni;
        if (n >= Ntot) continue;
        float4 r;
        r.x = acc[0][ni]; r.y = acc[1][ni]; r.z = acc[2][ni]; r.w = acc[3][ni];
        if (n >= bias_start) { r.x += bvals[0]; r.y += bvals[1]; r.z += bvals[2]; r.w += bvals[3]; }
        *(float4*)(out + (size_t)n * CDIM + m0 + ty * 4) = r;
    }
}

// ---------------------------------------------------------------------------
// Kernel 3: TW[j][c] = (txt_j / ||txt_j||) . out_w[:, c];  cconst[j] = (txt_j/||..||) . out_b
// grid (NTXT, 8), block 256 (8*256 = 2048 c-cols)
__global__ __launch_bounds__(256) void txtw_k(
    const float* __restrict__ txt, const float* __restrict__ out_w, const float* __restrict__ out_b,
    float* __restrict__ TW, float* __restrict__ cconst)
{
    __shared__ float ts[OUTD];
    __shared__ float red[256], redb[256];
    int j = blockIdx.x, cb = blockIdx.y, tid = threadIdx.x;

    float n2 = 0.f, db = 0.f;
    for (int o = tid; o < OUTD; o += 256) {
        float tv = txt[(size_t)j * OUTD + o];
        ts[o] = tv;
        n2 += tv * tv;
        db += tv * out_b[o];
    }
    red[tid] = n2; redb[tid] = db;
    __syncthreads();
    for (int s = 128; s > 0; s >>= 1) {
        if (tid < s) { red[tid] += red[tid + s]; redb[tid] += redb[tid + s]; }
        __syncthreads();
    }
    float inv = 1.f / sqrtf(red[0]);

    int c = cb * 256 + tid;
    float acc = 0.f;
    for (int o = 0; o < OUTD; ++o)
        acc += ts[o] * out_w[(size_t)o * CDIM + c];
    TW[(size_t)j * CDIM + c] = acc * inv;
    if (cb == 0 && tid == 0) cconst[j] = redb[0] * inv;
}

// ---------------------------------------------------------------------------
// Kernel 4: TV[col][h*NTXT+j] = sum_{d<64} TW[j][h*64+d] * V[col][h*64+d]
// grid (ceil(626/8), 32), block 256
__global__ __launch_bounds__(256) void tv_k(
    const float* __restrict__ TW, const float* __restrict__ Vbuf, float* __restrict__ TV)
{
    __shared__ float TWs[NTXT * HD];  // 45*64
    __shared__ float Vs[8 * HD];      // 8 cols * 64
    int cg = blockIdx.x, h = blockIdx.y, tid = threadIdx.x;
    int c0 = cg * 8;

    for (int idx = tid; idx < NTXT * HD; idx += 256) {
        int j = idx / HD, d = idx % HD;
        TWs[idx] = TW[(size_t)j * CDIM + h * HD + d];
    }
    for (int idx = tid; idx < 8 * HD; idx += 256) {
        int c = idx / HD, d = idx % HD;
        int col = c0 + c;
        Vs[idx] = (col < NKV) ? Vbuf[(size_t)col * CDIM + h * HD + d] : 0.f;
    }
    __syncthreads();

    for (int o = tid; o < 8 * NTXT; o += 256) {
        int c = o / NTXT, j = o % NTXT;
        int col = c0 + c;
        if (col >= NKV) continue;
        float acc = 0.f;
#pragma unroll
        for (int d = 0; d < HD; d += 4) {
            float4 tw = *(const float4*)&TWs[j * HD + d];
            float4 vv = *(const float4*)&Vs[c * HD + d];
            acc += tw.x * vv.x + tw.y * vv.y + tw.z * vv.z + tw.w * vv.w;
        }
        TV[(size_t)col * HJ + h * NTXT + j] = acc;
    }
}

// ---------------------------------------------------------------------------
// Kernel 5: per-patch attention scores + softmax + folded text logits + argmax -> bucket
// s0 (mean token) K-score = mean of per-pixel feature scores (linearity) -> no kmean needed.
// v_b folds into cconst implicitly? No: v_b lives in the pos columns of Vbuf -> inside TVpos. OK.
__global__ __launch_bounds__(256) void attn2_k(
    const float* __restrict__ Kbuf, const float* __restrict__ Qbuf,
    const float* __restrict__ TV, const float* __restrict__ cconst,
    int* __restrict__ bucket)
{
    __shared__ float qs[CDIM];
    __shared__ float scf[NHEAD][NTOK];   // feature part of scores (t=1..49); [h][0] = mean
    __shared__ float attn[NHEAD][NTOK];  // pos part, then final probs
    __shared__ float racc[HJ];           // per-(h,j) logit partials
    __shared__ float logit[NTXT];

    int p = blockIdx.x;
    int pi = p / WO, pj = p % WO;
    int tid = threadIdx.x;

    // q = Qm[p] + Qpos0 (Qbuf col NP has q_w*pos0 + q_b)
#pragma unroll
    for (int r = 0; r < 8; ++r) {
        int c = tid + 256 * r;
        qs[c] = Qbuf[(size_t)p * CDIM + c] + Qbuf[(size_t)NP * CDIM + c];
    }
    __syncthreads();

    // feature scores for t=1..49
    for (int pair = tid; pair < NHEAD * 49; pair += 256) {
        int h = pair / 49, t = pair % 49 + 1;
        const float* kb = Kbuf + (size_t)((pi + (t - 1) / 7) * WF + pj + (t - 1) % 7) * CDIM;
        int base = h * HD;
        float dot = 0.f;
#pragma unroll
        for (int d = 0; d < HD; d += 4) {
            float4 qv = *(const float4*)&qs[base + d];
            float4 kv = *(const float4*)&kb[base + d];
            dot += qv.x * kv.x + qv.y * kv.y + qv.z * kv.z + qv.w * kv.w;
        }
        scf[h][t] = dot;
    }
    // pos scores for t=0..49 (Kbuf pos cols carry k_w*pos_t + k_b)
    for (int pair = tid; pair < NHEAD * NTOK; pair += 256) {
        int h = pair / NTOK, t = pair % NTOK;
        const float* kp = Kbuf + (size_t)(PIX + t) * CDIM;
        int base = h * HD;
        float dot = 0.f;
#pragma unroll
        for (int d = 0; d < HD; d += 4) {
            float4 qv = *(const float4*)&qs[base + d];
            float4 kv = *(const float4*)&kp[base + d];
            dot += qv.x * kv.x + qv.y * kv.y + qv.z * kv.z + qv.w * kv.w;
        }
        attn[h][t] = dot;
    }
    __syncthreads();

    // softmax per head (50 tokens); token 0 feature part = mean of scf[1..49]
    if (tid < NHEAD) {
        int h = tid;
        float sF = 0.f;
        for (int t = 1; t < NTOK; ++t) sF += scf[h][t];
        scf[h][0] = sF * (1.f / 49.f);
        float m = -1e30f;
        for (int t = 0; t < NTOK; ++t) {
            float s = (scf[h][t] + attn[h][t]) * 0.125f;  // 1/sqrt(64)
            attn[h][t] = s;
            m = fmaxf(m, s);
        }
        float ssum = 0.f;
        for (int t = 0; t < NTOK; ++t) { float e = expf(attn[h][t] - m); attn[h][t] = e; ssum += e; }
        float invs = 1.f / ssum;
        for (int t = 0; t < NTOK; ++t) attn[h][t] *= invs;
    }
    __syncthreads();

    // folded pooling: logit partial per (h,j); mean-token TV = running mean of pixel TVs
    float lacc[6] = {}, macc[6] = {};
    for (int t = 1; t < NTOK; ++t) {
        const float* TVpix = TV + (size_t)((pi + (t - 1) / 7) * WF + pj + (t - 1) % 7) * HJ;
        const float* TVpos = TV + (size_t)(PIX + t) * HJ;
#pragma unroll
        for (int r = 0; r < 6; ++r) {
            int o = tid + 256 * r;
            if (o < HJ) {
                float a = attn[o / NTXT][t];
                float v1 = TVpix[o];
                lacc[r] += a * (v1 + TVpos[o]);
                macc[r] += v1;
            }
        }
    }
    {
        const float* TVp0 = TV + (size_t)PIX * HJ;
#pragma unroll
        for (int r = 0; r < 6; ++r) {
            int o = tid + 256 * r;
            if (o < HJ) {
                float a0 = attn[o / NTXT][0];
                lacc[r] += a0 * (macc[r] * (1.f / 49.f) + TVp0[o]);
                racc[o] = lacc[r];
            }
        }
    }
    __syncthreads();

    // reduce over heads, add const, argmax
    if (tid < NTXT) {
        float s = cconst[tid];
        for (int h = 0; h < NHEAD; ++h) s += racc[h * NTXT + tid];
        logit[tid] = s;
    }
    __syncthreads();
    if (tid == 0) {
        float best = logit[0]; int bi = 0;
        for (int j2 = 1; j2 < NTXT; ++j2)
            if (logit[j2] > best) { best = logit[j2]; bi = j2; }
        int bk = 0;
        const int bounds[5] = {8, 15, 22, 29, 36};
#pragma unroll
        for (int u = 0; u < 5; ++u) bk += (bi >= bounds[u]) ? 1 : 0;
        bucket[p] = bk;
    }
}

// ---------------------------------------------------------------------------
// Kernel 6: vote conv (7x7 ones, full padding) + channel argmax -> binary map value
__global__ void votes_k(const int* __restrict__ bucket, float* __restrict__ maxval) {
    __shared__ int bk[NP];
    int tid = threadIdx.x;
    if (tid < NP) bk[tid] = bucket[tid];
    __syncthreads();
    if (tid < PIX) {
        int y = tid / WF, x = tid % WF;
        int cnt[6] = {0, 0, 0, 0, 0, 0};
        int i0 = (y - 6 < 0) ? 0 : y - 6;
        int i1 = (y > HO - 1) ? HO - 1 : y;
        int j0 = (x - 6 < 0) ? 0 : x - 6;
        int j1 = (x > WO - 1) ? WO - 1 : x;
        for (int i = i0; i <= i1; ++i)
            for (int j = j0; j <= j1; ++j)
                cnt[bk[i * WO + j]]++;
        int best = cnt[0], bi = 0;
#pragma unroll
        for (int ch = 1; ch < 6; ++ch)
            if (cnt[ch] > best) { best = cnt[ch]; bi = ch; }
        maxval[tid] = (bi > 0) ? 0.044194173824159216f : 0.f;  // 1/sqrt(512)
    }
}

// ---------------------------------------------------------------------------
// Kernel 7: fill output (batch 0 = 0, batch 1 = maxval broadcast over 512 ch)
__global__ void fill_k(const float* __restrict__ maxval, float* __restrict__ out) {
    int idx = blockIdx.x * 256 + threadIdx.x;
    const int HALF = OUTD * PIX;  // 294912
    if (idx >= 2 * HALF) return;
    out[idx] = (idx < HALF) ? 0.f : maxval[idx % PIX];
}

// ---------------------------------------------------------------------------
extern "C" void kernel_launch(void* const* d_in, const int* in_sizes, int n_in,
                              void* d_out, int out_size, void* d_ws, size_t ws_size,
                              hipStream_t stream) {
    const float* imgf = (const float*)d_in[0];
    const float* txt  = (const float*)d_in[1];
    const float* pos  = (const float*)d_in[2];
    const float* q_w  = (const float*)d_in[3];
    const float* q_b  = (const float*)d_in[4];
    const float* k_w  = (const float*)d_in[5];
    const float* k_b  = (const float*)d_in[6];
    const float* v_w  = (const float*)d_in[7];
    const float* v_b  = (const float*)d_in[8];
    const float* o_w  = (const float*)d_in[9];
    const float* o_b  = (const float*)d_in[10];

    const float* feat1 = imgf + (size_t)1 * CDIM * PIX;  // only batch B-1=1 matters

    float* ws = (float*)d_ws;
    float* Kbuf = ws;                         // 626*2048
    float* Vbuf = Kbuf + (size_t)NKV * CDIM;  // 626*2048
    float* Qbuf = Vbuf + (size_t)NKV * CDIM;  // 325*2048
    float* mf   = Qbuf + (size_t)NQ * CDIM;   // 2048*324
    float* TW   = mf + (size_t)CDIM * NP;     // 45*2048
    float* cconst = TW + (size_t)NTXT * CDIM; // 45
    float* TV   = cconst + 64;                // 626*1440
    int*   bucket = (int*)(TV + (size_t)NKV * HJ);
    float* maxval = (float*)(bucket + NP);

    meanfeat_k<<<dim3((CDIM * NP + 255) / 256), dim3(256), 0, stream>>>(feat1, mf);
    gemm_k<<<dim3(CDIM / 64, (NKV + 63) / 64, 3), dim3(256), 0, stream>>>(
        k_w, v_w, q_w, feat1, mf, pos, k_b, v_b, q_b, Kbuf, Vbuf, Qbuf);
    txtw_k<<<dim3(NTXT, CDIM / 256), dim3(256), 0, stream>>>(txt, o_w, o_b, TW, cconst);
    tv_k<<<dim3((NKV + 7) / 8, NHEAD), dim3(256), 0, stream>>>(TW, Vbuf, TV);
    attn2_k<<<dim3(NP), dim3(256), 0, stream>>>(Kbuf, Qbuf, TV, cconst, bucket);
    votes_k<<<dim3(1), dim3(576), 0, stream>>>(bucket, maxval);
    fill_k<<<dim3((2 * OUTD * PIX + 255) / 256), dim3(256), 0, stream>>>(maxval, (float*)d_out);
}

// Round 3
// 425.475 us; speedup vs baseline: 1.4144x; 1.0548x over previous
//
#include <hip/hip_runtime.h>
#include <math.h>

#define CDIM 2048
#define HF 24
#define WF 24
#define PIX 576
#define HO 18
#define WO 18
#define NP 324
#define NHEAD 32
#define HD 64
#define NTOK 50
#define NTXT 45
#define OUTD 512
#define NKV 626
#define HJ (NHEAD * NTXT)   // 1440
#define NROWS 640           // padded B rows: 576 pixels + 50 pos + 14 zero

typedef __attribute__((ext_vector_type(8))) short short8;
typedef __attribute__((ext_vector_type(4))) float f32x4;

__device__ inline unsigned bf16rn(float x) {
    unsigned u = __float_as_uint(x);
    return (u + 0x7FFFu + ((u >> 16) & 1u)) >> 16;
}
__device__ inline float bf16tof(unsigned h) { return __uint_as_float(h << 16); }

// ---------------------------------------------------------------------------
// Split the 3 weight matrices into hi/lo bf16 (same [m][k] layout).
__global__ void split_w_k(const float* __restrict__ kw, const float* __restrict__ vw, const float* __restrict__ qw,
                          ushort* __restrict__ WhK, ushort* __restrict__ WlK,
                          ushort* __restrict__ WhV, ushort* __restrict__ WlV,
                          ushort* __restrict__ WhQ, ushort* __restrict__ WlQ) {
    int g = blockIdx.x * 256 + threadIdx.x;      // 3 * 1048576 threads, 4 elems each
    int sel = g >> 20;
    int off = (g & 1048575) * 4;
    const float* src = sel == 0 ? kw : sel == 1 ? vw : qw;
    ushort* dh = sel == 0 ? WhK : sel == 1 ? WhV : WhQ;
    ushort* dl = sel == 0 ? WlK : sel == 1 ? WlV : WlQ;
    float4 v = *(const float4*)(src + off);
    float xs[4] = {v.x, v.y, v.z, v.w};
    ushort h[4], l[4];
#pragma unroll
    for (int i = 0; i < 4; ++i) {
        unsigned hh = bf16rn(xs[i]);
        h[i] = (ushort)hh;
        l[i] = (ushort)bf16rn(xs[i] - bf16tof(hh));
    }
    *(ushort4*)(dh + off) = make_ushort4(h[0], h[1], h[2], h[3]);
    *(ushort4*)(dl + off) = make_ushort4(l[0], l[1], l[2], l[3]);
}

// ---------------------------------------------------------------------------
// Transpose+split feat1 [2048][576] f32 -> Xh/Xl [640][2048] bf16 rows 0..575.
__global__ __launch_bounds__(256) void split_xt_k(const float* __restrict__ feat1,
                                                  ushort* __restrict__ Xh, ushort* __restrict__ Xl) {
    __shared__ float tile[64][65];
    int n0 = blockIdx.x * 64, c0 = blockIdx.y * 64, tid = threadIdx.x;
#pragma unroll
    for (int i = 0; i < 16; ++i) {
        int idx = tid + i * 256;
        int cc = idx >> 6, nn = idx & 63;
        tile[cc][nn] = feat1[(size_t)(c0 + cc) * PIX + n0 + nn];
    }
    __syncthreads();
#pragma unroll
    for (int i = 0; i < 16; ++i) {
        int idx = tid + i * 256;
        int nn = idx >> 6, cc = idx & 63;
        float x = tile[cc][nn];
        unsigned hh = bf16rn(x);
        Xh[(size_t)(n0 + nn) * CDIM + c0 + cc] = (ushort)hh;
        Xl[(size_t)(n0 + nn) * CDIM + c0 + cc] = (ushort)bf16rn(x - bf16tof(hh));
    }
}

// ---------------------------------------------------------------------------
// Rows 576..639 of Xh/Xl: pos tokens (split) for r<50, zeros for pad rows.
__global__ void split_pos_k(const float* __restrict__ pos,
                            ushort* __restrict__ Xh, ushort* __restrict__ Xl) {
    int g = blockIdx.x * 256 + threadIdx.x;     // 32768 threads, 4 elems each
    int r = g >> 9;                              // 0..63
    int c = (g & 511) * 4;
    float4 v = make_float4(0.f, 0.f, 0.f, 0.f);
    if (r < 50) v = *(const float4*)(pos + (size_t)r * CDIM + c);
    float xs[4] = {v.x, v.y, v.z, v.w};
    ushort h[4], l[4];
#pragma unroll
    for (int i = 0; i < 4; ++i) {
        unsigned hh = bf16rn(xs[i]);
        h[i] = (ushort)hh;
        l[i] = (ushort)bf16rn(xs[i] - bf16tof(hh));
    }
    size_t o = (size_t)(576 + r) * CDIM + c;
    *(ushort4*)(Xh + o) = make_ushort4(h[0], h[1], h[2], h[3]);
    *(ushort4*)(Xl + o) = make_ushort4(l[0], l[1], l[2], l[3]);
}

// ---------------------------------------------------------------------------
// Split-bf16 MFMA GEMM: out[n][m] = sum_k W[m][k]*X[n][k]  (X pre-transposed)
// 3 products: WhXh + WhXl + WlXh. Tile 128x128, BK=32, 4 waves (2x2 of 64x64).
// LDS holds fragments in native MFMA lane order -> stride-1 ds ops.
__global__ __launch_bounds__(256, 2) void gemm_bf16_k(
    const ushort* __restrict__ WhK, const ushort* __restrict__ WlK,
    const ushort* __restrict__ WhV, const ushort* __restrict__ WlV,
    const ushort* __restrict__ WhQ, const ushort* __restrict__ WlQ,
    const ushort* __restrict__ Xh, const ushort* __restrict__ Xl,
    const float* __restrict__ k_b, const float* __restrict__ v_b, const float* __restrict__ q_b,
    float* __restrict__ Kbuf, float* __restrict__ Vbuf, float* __restrict__ Qfull)
{
    __shared__ char smem[32768];   // [arr 0..3: Ah,Al,Bh,Bl][8KB = 8 slots x 1KB]
    int z = blockIdx.z;
    const ushort* Wh = z == 0 ? WhK : z == 1 ? WhV : WhQ;
    const ushort* Wl = z == 0 ? WlK : z == 1 ? WlV : WlQ;
    const float* bias = z == 0 ? k_b : z == 1 ? v_b : q_b;
    float* out = z == 0 ? Kbuf : z == 1 ? Vbuf : Qfull;
    int m0 = blockIdx.x * 128, n0 = blockIdx.y * 128;

    int tid = threadIdx.x, wid = tid >> 6, lane = tid & 63;
    int lrow = lane & 15, lk = lane >> 4;

    // staging source: wave 0 -> Ah (Wh), 1 -> Al (Wl), 2 -> Bh (Xh), 3 -> Bl (Xl)
    const char* gsrc;
    {
        const ushort* arr = wid == 0 ? Wh : wid == 1 ? Wl : wid == 2 ? Xh : Xl;
        int rb = (wid < 2 ? m0 : n0) + lrow;
        gsrc = (const char*)(arr + (size_t)rb * CDIM + lk * 8);
    }
    char* ldsarr = smem + wid * 8192;

    uint4 r[8];
#pragma unroll
    for (int s = 0; s < 8; ++s) r[s] = *(const uint4*)(gsrc + (size_t)s * 65536);

    f32x4 acc[4][4];
#pragma unroll
    for (int a = 0; a < 4; ++a)
#pragma unroll
        for (int b = 0; b < 4; ++b) acc[a][b] = (f32x4)0.f;

    int wm = wid >> 1, wn = wid & 1;

    for (int t = 0; t < 64; ++t) {
        // publish tile t
#pragma unroll
        for (int s = 0; s < 8; ++s) *(uint4*)(ldsarr + s * 1024 + lane * 16) = r[s];
        // prefetch tile t+1 into regs (flies during compute)
        if (t < 63) {
            const char* gs2 = gsrc + (size_t)(t + 1) * 64;
#pragma unroll
            for (int s = 0; s < 8; ++s) r[s] = *(const uint4*)(gs2 + (size_t)s * 65536);
        }
        asm volatile("s_waitcnt lgkmcnt(0)" ::: "memory");
        __builtin_amdgcn_s_barrier();
        asm volatile("" ::: "memory");

        short8 ah[4], al[4];
#pragma unroll
        for (int fm = 0; fm < 4; ++fm) {
            ah[fm] = *(const short8*)(smem +        ((wm * 4 + fm) * 64 + lane) * 16);
            al[fm] = *(const short8*)(smem + 8192 + ((wm * 4 + fm) * 64 + lane) * 16);
        }
#pragma unroll
        for (int fn = 0; fn < 4; ++fn) {
            short8 bh = *(const short8*)(smem + 16384 + ((wn * 4 + fn) * 64 + lane) * 16);
            short8 bl = *(const short8*)(smem + 24576 + ((wn * 4 + fn) * 64 + lane) * 16);
#pragma unroll
            for (int fm = 0; fm < 4; ++fm) {
                acc[fm][fn] = __builtin_amdgcn_mfma_f32_16x16x32_bf16(ah[fm], bh, acc[fm][fn], 0, 0, 0);
                acc[fm][fn] = __builtin_amdgcn_mfma_f32_16x16x32_bf16(ah[fm], bl, acc[fm][fn], 0, 0, 0);
                acc[fm][fn] = __builtin_amdgcn_mfma_f32_16x16x32_bf16(al[fm], bh, acc[fm][fn], 0, 0, 0);
            }
        }
        asm volatile("" ::: "memory");
        __builtin_amdgcn_s_barrier();
    }

    // epilogue: C/D layout col=lane&15, row=(lane>>4)*4+reg (m89-verified)
#pragma unroll
    for (int fm = 0; fm < 4; ++fm) {
        int mg = m0 + wm * 64 + fm * 16 + (lane >> 4) * 4;
        float4 bv = *(const float4*)(bias + mg);
#pragma unroll
        for (int fn = 0; fn < 4; ++fn) {
            int ng = n0 + wn * 64 + fn * 16 + (lane & 15);
            f32x4 o = acc[fm][fn];
            if (ng >= PIX) { o[0] += bv.x; o[1] += bv.y; o[2] += bv.z; o[3] += bv.w; }
            *(f32x4*)(out + (size_t)ng * CDIM + mg) = o;
        }
    }
}

// ---------------------------------------------------------------------------
// Qm[p][c] = mean over 7x7 window of Qfull pixel cols + Qfull[576] (pos0+bias)
__global__ __launch_bounds__(256) void qmean_k(const float* __restrict__ Qfull, float* __restrict__ Qm) {
    int p = blockIdx.x;
    int i = p / WO, j = p % WO;
    int tid = threadIdx.x;
    float s[8] = {};
    for (int t = 0; t < 49; ++t) {
        int px = (i + t / 7) * WF + (j + t % 7);
        const float* qr = Qfull + (size_t)px * CDIM;
#pragma unroll
        for (int r = 0; r < 8; ++r) s[r] += qr[tid + 256 * r];
    }
    const float* p0 = Qfull + (size_t)PIX * CDIM;
#pragma unroll
    for (int r = 0; r < 8; ++r) {
        int c = tid + 256 * r;
        Qm[(size_t)p * CDIM + c] = s[r] * (1.f / 49.f) + p0[c];
    }
}

// ---------------------------------------------------------------------------
// TW[j][c] = (txt_j/||txt_j||) . out_w[:,c];  cconst[j] = (txt_j/||..||) . out_b
__global__ __launch_bounds__(256) void txtw_k(
    const float* __restrict__ txt, const float* __restrict__ out_w, const float* __restrict__ out_b,
    float* __restrict__ TW, float* __restrict__ cconst)
{
    __shared__ float ts[OUTD];
    __shared__ float red[256], redb[256];
    int j = blockIdx.x, cb = blockIdx.y, tid = threadIdx.x;

    float n2 = 0.f, db = 0.f;
    for (int o = tid; o < OUTD; o += 256) {
        float tv = txt[(size_t)j * OUTD + o];
        ts[o] = tv;
        n2 += tv * tv;
        db += tv * out_b[o];
    }
    red[tid] = n2; redb[tid] = db;
    __syncthreads();
    for (int s = 128; s > 0; s >>= 1) {
        if (tid < s) { red[tid] += red[tid + s]; redb[tid] += redb[tid + s]; }
        __syncthreads();
    }
    float inv = 1.f / sqrtf(red[0]);

    int c = cb * 256 + tid;
    float acc = 0.f;
    for (int o = 0; o < OUTD; ++o)
        acc += ts[o] * out_w[(size_t)o * CDIM + c];
    TW[(size_t)j * CDIM + c] = acc * inv;
    if (cb == 0 && tid == 0) cconst[j] = redb[0] * inv;
}

// ---------------------------------------------------------------------------
// TV[col][h*NTXT+j] = sum_d TW[j][h*64+d] * V[col][h*64+d]
__global__ __launch_bounds__(256) void tv_k(
    const float* __restrict__ TW, const float* __restrict__ Vbuf, float* __restrict__ TV)
{
    __shared__ float TWs[NTXT * HD];
    __shared__ float Vs[8 * HD];
    int cg = blockIdx.x, h = blockIdx.y, tid = threadIdx.x;
    int c0 = cg * 8;

    for (int idx = tid; idx < NTXT * HD; idx += 256) {
        int j = idx / HD, d = idx % HD;
        TWs[idx] = TW[(size_t)j * CDIM + h * HD + d];
    }
    for (int idx = tid; idx < 8 * HD; idx += 256) {
        int c = idx / HD, d = idx % HD;
        int col = c0 + c;
        Vs[idx] = (col < NKV) ? Vbuf[(size_t)col * CDIM + h * HD + d] : 0.f;
    }
    __syncthreads();

    for (int o = tid; o < 8 * NTXT; o += 256) {
        int c = o / NTXT, j = o % NTXT;
        int col = c0 + c;
        if (col >= NKV) continue;
        float acc = 0.f;
#pragma unroll
        for (int d = 0; d < HD; d += 4) {
            float4 tw = *(const float4*)&TWs[j * HD + d];
            float4 vv = *(const float4*)&Vs[c * HD + d];
            acc += tw.x * vv.x + tw.y * vv.y + tw.z * vv.z + tw.w * vv.w;
        }
        TV[(size_t)col * HJ + h * NTXT + j] = acc;
    }
}

// ---------------------------------------------------------------------------
// Per-patch attention + folded text logits + argmax -> bucket
__global__ __launch_bounds__(256) void attn2_k(
    const float* __restrict__ Kbuf, const float* __restrict__ Qm,
    const float* __restrict__ TV, const float* __restrict__ cconst,
    int* __restrict__ bucket)
{
    __shared__ float qs[CDIM];
    __shared__ float scf[NHEAD][NTOK];
    __shared__ float attn[NHEAD][NTOK];
    __shared__ float racc[HJ];
    __shared__ float logit[NTXT];

    int p = blockIdx.x;
    int pi = p / WO, pj = p % WO;
    int tid = threadIdx.x;

#pragma unroll
    for (int r = 0; r < 8; ++r) {
        int c = tid + 256 * r;
        qs[c] = Qm[(size_t)p * CDIM + c];
    }
    __syncthreads();

    for (int pair = tid; pair < NHEAD * 49; pair += 256) {
        int h = pair / 49, t = pair % 49 + 1;
        const float* kb = Kbuf + (size_t)((pi + (t - 1) / 7) * WF + pj + (t - 1) % 7) * CDIM;
        int base = h * HD;
        float dot = 0.f;
#pragma unroll
        for (int d = 0; d < HD; d += 4) {
            float4 qv = *(const float4*)&qs[base + d];
            float4 kv = *(const float4*)&kb[base + d];
            dot += qv.x * kv.x + qv.y * kv.y + qv.z * kv.z + qv.w * kv.w;
        }
        scf[h][t] = dot;
    }
    for (int pair = tid; pair < NHEAD * NTOK; pair += 256) {
        int h = pair / NTOK, t = pair % NTOK;
        const float* kp = Kbuf + (size_t)(PIX + t) * CDIM;
        int base = h * HD;
        float dot = 0.f;
#pragma unroll
        for (int d = 0; d < HD; d += 4) {
            float4 qv = *(const float4*)&qs[base + d];
            float4 kv = *(const float4*)&kp[base + d];
            dot += qv.x * kv.x + qv.y * kv.y + qv.z * kv.z + qv.w * kv.w;
        }
        attn[h][t] = dot;
    }
    __syncthreads();

    if (tid < NHEAD) {
        int h = tid;
        float sF = 0.f;
        for (int t = 1; t < NTOK; ++t) sF += scf[h][t];
        scf[h][0] = sF * (1.f / 49.f);
        float m = -1e30f;
        for (int t = 0; t < NTOK; ++t) {
            float s = (scf[h][t] + attn[h][t]) * 0.125f;
            attn[h][t] = s;
            m = fmaxf(m, s);
        }
        float ssum = 0.f;
        for (int t = 0; t < NTOK; ++t) { float e = expf(attn[h][t] - m); attn[h][t] = e; ssum += e; }
        float invs = 1.f / ssum;
        for (int t = 0; t < NTOK; ++t) attn[h][t] *= invs;
    }
    __syncthreads();

    float lacc[6] = {}, macc[6] = {};
    for (int t = 1; t < NTOK; ++t) {
        const float* TVpix = TV + (size_t)((pi + (t - 1) / 7) * WF + pj + (t - 1) % 7) * HJ;
        const float* TVpos = TV + (size_t)(PIX + t) * HJ;
#pragma unroll
        for (int r = 0; r < 6; ++r) {
            int o = tid + 256 * r;
            if (o < HJ) {
                float a = attn[o / NTXT][t];
                float v1 = TVpix[o];
                lacc[r] += a * (v1 + TVpos[o]);
                macc[r] += v1;
            }
        }
    }
    {
        const float* TVp0 = TV + (size_t)PIX * HJ;
#pragma unroll
        for (int r = 0; r < 6; ++r) {
            int o = tid + 256 * r;
            if (o < HJ) {
                float a0 = attn[o / NTXT][0];
                lacc[r] += a0 * (macc[r] * (1.f / 49.f) + TVp0[o]);
                racc[o] = lacc[r];
            }
        }
    }
    __syncthreads();

    if (tid < NTXT) {
        float s = cconst[tid];
        for (int h = 0; h < NHEAD; ++h) s += racc[h * NTXT + tid];
        logit[tid] = s;
    }
    __syncthreads();
    if (tid == 0) {
        float best = logit[0]; int bi = 0;
        for (int j2 = 1; j2 < NTXT; ++j2)
            if (logit[j2] > best) { best = logit[j2]; bi = j2; }
        int bk = 0;
        const int bounds[5] = {8, 15, 22, 29, 36};
#pragma unroll
        for (int u = 0; u < 5; ++u) bk += (bi >= bounds[u]) ? 1 : 0;
        bucket[p] = bk;
    }
}

// ---------------------------------------------------------------------------
__global__ void votes_k(const int* __restrict__ bucket, float* __restrict__ maxval) {
    __shared__ int bk[NP];
    int tid = threadIdx.x;
    if (tid < NP) bk[tid] = bucket[tid];
    __syncthreads();
    if (tid < PIX) {
        int y = tid / WF, x = tid % WF;
        int cnt[6] = {0, 0, 0, 0, 0, 0};
        int i0 = (y - 6 < 0) ? 0 : y - 6;
        int i1 = (y > HO - 1) ? HO - 1 : y;
        int j0 = (x - 6 < 0) ? 0 : x - 6;
        int j1 = (x > WO - 1) ? WO - 1 : x;
        for (int i = i0; i <= i1; ++i)
            for (int j = j0; j <= j1; ++j)
                cnt[bk[i * WO + j]]++;
        int best = cnt[0], bi = 0;
#pragma unroll
        for (int ch = 1; ch < 6; ++ch)
            if (cnt[ch] > best) { best = cnt[ch]; bi = ch; }
        maxval[tid] = (bi > 0) ? 0.044194173824159216f : 0.f;
    }
}

__global__ void fill_k(const float* __restrict__ maxval, float* __restrict__ out) {
    int idx = blockIdx.x * 256 + threadIdx.x;
    const int HALF = OUTD * PIX;
    if (idx >= 2 * HALF) return;
    out[idx] = (idx < HALF) ? 0.f : maxval[idx % PIX];
}

// ---------------------------------------------------------------------------
extern "C" void kernel_launch(void* const* d_in, const int* in_sizes, int n_in,
                              void* d_out, int out_size, void* d_ws, size_t ws_size,
                              hipStream_t stream) {
    const float* imgf = (const float*)d_in[0];
    const float* txt  = (const float*)d_in[1];
    const float* pos  = (const float*)d_in[2];
    const float* q_w  = (const float*)d_in[3];
    const float* q_b  = (const float*)d_in[4];
    const float* k_w  = (const float*)d_in[5];
    const float* k_b  = (const float*)d_in[6];
    const float* v_w  = (const float*)d_in[7];
    const float* v_b  = (const float*)d_in[8];
    const float* o_w  = (const float*)d_in[9];
    const float* o_b  = (const float*)d_in[10];

    const float* feat1 = imgf + (size_t)1 * CDIM * PIX;   // only batch B-1=1 matters

    float* ws = (float*)d_ws;
    float* Kbuf  = ws;                                   // 640*2048
    float* Vbuf  = Kbuf + (size_t)NROWS * CDIM;
    float* Qfull = Vbuf + (size_t)NROWS * CDIM;
    float* Qm    = Qfull + (size_t)NROWS * CDIM;         // 324*2048
    float* TW    = Qm + (size_t)NP * CDIM;               // 45*2048
    float* cconst = TW + (size_t)NTXT * CDIM;            // 64
    float* TV    = cconst + 64;                          // 626*1440
    int*   bucket = (int*)(TV + (size_t)NKV * HJ);       // 324
    float* maxval = (float*)(bucket + NP);               // 576
    size_t foff = (size_t)(maxval + 576 - ws);
    foff = (foff + 3) & ~(size_t)3;                      // 16B align
    ushort* WhK = (ushort*)(ws + foff);                  // each 2048*2048
    ushort* WlK = WhK + (size_t)CDIM * CDIM;
    ushort* WhV = WlK + (size_t)CDIM * CDIM;
    ushort* WlV = WhV + (size_t)CDIM * CDIM;
    ushort* WhQ = WlV + (size_t)CDIM * CDIM;
    ushort* WlQ = WhQ + (size_t)CDIM * CDIM;
    ushort* Xh  = WlQ + (size_t)CDIM * CDIM;             // 640*2048
    ushort* Xl  = Xh + (size_t)NROWS * CDIM;

    split_w_k<<<dim3(12288), dim3(256), 0, stream>>>(k_w, v_w, q_w, WhK, WlK, WhV, WlV, WhQ, WlQ);
    split_xt_k<<<dim3(9, 32), dim3(256), 0, stream>>>(feat1, Xh, Xl);
    split_pos_k<<<dim3(128), dim3(256), 0, stream>>>(pos, Xh, Xl);
    gemm_bf16_k<<<dim3(16, 5, 3), dim3(256), 0, stream>>>(WhK, WlK, WhV, WlV, WhQ, WlQ,
                                                          Xh, Xl, k_b, v_b, q_b, Kbuf, Vbuf, Qfull);
    qmean_k<<<dim3(NP), dim3(256), 0, stream>>>(Qfull, Qm);
    txtw_k<<<dim3(NTXT, 8), dim3(256), 0, stream>>>(txt, o_w, o_b, TW, cconst);
    tv_k<<<dim3(79, 32), dim3(256), 0, stream>>>(TW, Vbuf, TV);
    attn2_k<<<dim3(NP), dim3(256), 0, stream>>>(Kbuf, Qm, TV, cconst, bucket);
    votes_k<<<dim3(1), dim3(576), 0, stream>>>(bucket, maxval);
    fill_k<<<dim3(2304), dim3(256), 0, stream>>>(maxval, (float*)d_out);
}

// Round 4
// 328.984 us; speedup vs baseline: 1.8292x; 1.2933x over previous
//
#include <hip/hip_runtime.h>
#include <math.h>

#define CDIM 2048
#define HF 24
#define WF 24
#define PIX 576
#define HO 18
#define WO 18
#define NP 324
#define NHEAD 32
#define HD 64
#define NTOK 50
#define NTXT 45
#define OUTD 512
#define NKV 626
#define HJ (NHEAD * NTXT)   // 1440
#define NROWS 640           // padded B rows: 576 pixels + 50 pos + 14 zero

typedef __attribute__((ext_vector_type(8))) short short8;
typedef __attribute__((ext_vector_type(4))) float f32x4;
typedef __attribute__((address_space(1))) const void as1c_void;
typedef __attribute__((address_space(3))) void as3_void;

__device__ inline unsigned bf16rn(float x) {
    unsigned u = __float_as_uint(x);
    return (u + 0x7FFFu + ((u >> 16) & 1u)) >> 16;
}
__device__ inline float bf16tof(unsigned h) { return __uint_as_float(h << 16); }

// ---------------------------------------------------------------------------
// Split the 3 weight matrices into hi/lo bf16 (same [m][k] layout).
__global__ void split_w_k(const float* __restrict__ kw, const float* __restrict__ vw, const float* __restrict__ qw,
                          ushort* __restrict__ WhK, ushort* __restrict__ WlK,
                          ushort* __restrict__ WhV, ushort* __restrict__ WlV,
                          ushort* __restrict__ WhQ, ushort* __restrict__ WlQ) {
    int g = blockIdx.x * 256 + threadIdx.x;      // 3 * 1048576 threads, 4 elems each
    int sel = g >> 20;
    int off = (g & 1048575) * 4;
    const float* src = sel == 0 ? kw : sel == 1 ? vw : qw;
    ushort* dh = sel == 0 ? WhK : sel == 1 ? WhV : WhQ;
    ushort* dl = sel == 0 ? WlK : sel == 1 ? WlV : WlQ;
    float4 v = *(const float4*)(src + off);
    float xs[4] = {v.x, v.y, v.z, v.w};
    ushort h[4], l[4];
#pragma unroll
    for (int i = 0; i < 4; ++i) {
        unsigned hh = bf16rn(xs[i]);
        h[i] = (ushort)hh;
        l[i] = (ushort)bf16rn(xs[i] - bf16tof(hh));
    }
    *(ushort4*)(dh + off) = make_ushort4(h[0], h[1], h[2], h[3]);
    *(ushort4*)(dl + off) = make_ushort4(l[0], l[1], l[2], l[3]);
}

// ---------------------------------------------------------------------------
// Transpose+split feat1 [2048][576] f32 -> Xh/Xl [640][2048] bf16 rows 0..575.
__global__ __launch_bounds__(256) void split_xt_k(const float* __restrict__ feat1,
                                                  ushort* __restrict__ Xh, ushort* __restrict__ Xl) {
    __shared__ float tile[64][65];
    int n0 = blockIdx.x * 64, c0 = blockIdx.y * 64, tid = threadIdx.x;
#pragma unroll
    for (int i = 0; i < 16; ++i) {
        int idx = tid + i * 256;
        int cc = idx >> 6, nn = idx & 63;
        tile[cc][nn] = feat1[(size_t)(c0 + cc) * PIX + n0 + nn];
    }
    __syncthreads();
#pragma unroll
    for (int i = 0; i < 16; ++i) {
        int idx = tid + i * 256;
        int nn = idx >> 6, cc = idx & 63;
        float x = tile[cc][nn];
        unsigned hh = bf16rn(x);
        Xh[(size_t)(n0 + nn) * CDIM + c0 + cc] = (ushort)hh;
        Xl[(size_t)(n0 + nn) * CDIM + c0 + cc] = (ushort)bf16rn(x - bf16tof(hh));
    }
}

// ---------------------------------------------------------------------------
// Rows 576..639 of Xh/Xl: pos tokens (split) for r<50, zeros for pad rows.
__global__ void split_pos_k(const float* __restrict__ pos,
                            ushort* __restrict__ Xh, ushort* __restrict__ Xl) {
    int g = blockIdx.x * 256 + threadIdx.x;     // 32768 threads, 4 elems each
    int r = g >> 9;                              // 0..63
    int c = (g & 511) * 4;
    float4 v = make_float4(0.f, 0.f, 0.f, 0.f);
    if (r < 50) v = *(const float4*)(pos + (size_t)r * CDIM + c);
    float xs[4] = {v.x, v.y, v.z, v.w};
    ushort h[4], l[4];
#pragma unroll
    for (int i = 0; i < 4; ++i) {
        unsigned hh = bf16rn(xs[i]);
        h[i] = (ushort)hh;
        l[i] = (ushort)bf16rn(xs[i] - bf16tof(hh));
    }
    size_t o = (size_t)(576 + r) * CDIM + c;
    *(ushort4*)(Xh + o) = make_ushort4(h[0], h[1], h[2], h[3]);
    *(ushort4*)(Xl + o) = make_ushort4(l[0], l[1], l[2], l[3]);
}

// ---------------------------------------------------------------------------
// Split-bf16 MFMA GEMM, 2-phase async pipeline:
//   out[n][m] = sum_k W[m][k]*X[n][k]   (X pre-transposed [n][k])
// 3 products: WhXh + WhXl + WlXh. Tile 128m x 64n, BK=32, 4 waves (2x2, wave=64x32).
// Double-buffered LDS (2 x 24KB), staged via global_load_lds width=16 (linear
// fragment-order dest = slot_base + lane*16), one __syncthreads (vmcnt drain)/tile.
#define BUFB 24576
__global__ __launch_bounds__(256, 2) void gemm_bf16_k(
    const ushort* __restrict__ WhK, const ushort* __restrict__ WlK,
    const ushort* __restrict__ WhV, const ushort* __restrict__ WlV,
    const ushort* __restrict__ WhQ, const ushort* __restrict__ WlQ,
    const ushort* __restrict__ Xh, const ushort* __restrict__ Xl,
    const float* __restrict__ k_b, const float* __restrict__ v_b, const float* __restrict__ q_b,
    float* __restrict__ Kbuf, float* __restrict__ Vbuf, float* __restrict__ Qfull)
{
    __shared__ char smem[2 * BUFB];
    int z = blockIdx.z;
    const ushort* Wh = z == 0 ? WhK : z == 1 ? WhV : WhQ;
    const ushort* Wl = z == 0 ? WlK : z == 1 ? WlV : WlQ;
    const float* bias = z == 0 ? k_b : z == 1 ? v_b : q_b;
    float* out = z == 0 ? Kbuf : z == 1 ? Vbuf : Qfull;
    int m0 = blockIdx.x * 128, n0 = blockIdx.y * 64;

    int tid = threadIdx.x, wid = tid >> 6, lane = tid & 63;
    int lrow = lane & 15, lk = lane >> 4;
    int wm = wid >> 1, wn = wid & 1;

    // per-wave staging assignment: 24 slot-loads/block, 6 per wave.
    // g<8: Ah slot g | g<16: Al slot g-8 | g<20: Bh slot g-16 | else Bl slot g-20
    const char* gsrc[6];
    int ldsoff[6];
#pragma unroll
    for (int i = 0; i < 6; ++i) {
        int g = wid * 6 + i;
        const ushort* src; int row; int off;
        if (g < 8)       { src = Wh; row = m0 + g * 16 + lrow;        off = g * 1024; }
        else if (g < 16) { src = Wl; row = m0 + (g - 8) * 16 + lrow;  off = 8192 + (g - 8) * 1024; }
        else if (g < 20) { src = Xh; row = n0 + (g - 16) * 16 + lrow; off = 16384 + (g - 16) * 1024; }
        else             { src = Xl; row = n0 + (g - 20) * 16 + lrow; off = 20480 + (g - 20) * 1024; }
        gsrc[i] = (const char*)(src + (size_t)row * CDIM + lk * 8);
        ldsoff[i] = off;
    }

    f32x4 acc[4][2];
#pragma unroll
    for (int a = 0; a < 4; ++a)
#pragma unroll
        for (int b = 0; b < 2; ++b) acc[a][b] = (f32x4)0.f;

    // prologue: stage tile 0 into buffer 0
#pragma unroll
    for (int i = 0; i < 6; ++i)
        __builtin_amdgcn_global_load_lds((as1c_void*)(gsrc[i]),
                                         (as3_void*)(smem + ldsoff[i]), 16, 0, 0);
    __syncthreads();

    int cur = 0;
    for (int t = 0; t < 64; ++t) {
        char* rbuf = smem + cur * BUFB;
        char* wbuf = smem + (cur ^ 1) * BUFB;
        // stage tile t+1 (flies under the ds_read + MFMA phase)
        if (t < 63) {
#pragma unroll
            for (int i = 0; i < 6; ++i)
                __builtin_amdgcn_global_load_lds((as1c_void*)(gsrc[i] + (size_t)(t + 1) * 64),
                                                 (as3_void*)(wbuf + ldsoff[i]), 16, 0, 0);
        }

        short8 ah[4], al[4];
#pragma unroll
        for (int fm = 0; fm < 4; ++fm) {
            int s = wm * 4 + fm;
            ah[fm] = *(const short8*)(rbuf + s * 1024 + lane * 16);
            al[fm] = *(const short8*)(rbuf + 8192 + s * 1024 + lane * 16);
        }
        short8 bh[2], bl[2];
#pragma unroll
        for (int fn = 0; fn < 2; ++fn) {
            int s = wn * 2 + fn;
            bh[fn] = *(const short8*)(rbuf + 16384 + s * 1024 + lane * 16);
            bl[fn] = *(const short8*)(rbuf + 20480 + s * 1024 + lane * 16);
        }
#pragma unroll
        for (int fn = 0; fn < 2; ++fn)
#pragma unroll
            for (int fm = 0; fm < 4; ++fm) {
                acc[fm][fn] = __builtin_amdgcn_mfma_f32_16x16x32_bf16(ah[fm], bh[fn], acc[fm][fn], 0, 0, 0);
                acc[fm][fn] = __builtin_amdgcn_mfma_f32_16x16x32_bf16(ah[fm], bl[fn], acc[fm][fn], 0, 0, 0);
                acc[fm][fn] = __builtin_amdgcn_mfma_f32_16x16x32_bf16(al[fm], bh[fn], acc[fm][fn], 0, 0, 0);
            }
        __syncthreads();   // drains vmcnt (staged loads) + ensures rbuf reads done
        cur ^= 1;
    }

    // epilogue: C/D layout col(n)=lane&15, row(m)=(lane>>4)*4+reg (m89-verified)
#pragma unroll
    for (int fm = 0; fm < 4; ++fm) {
        int mg = m0 + wm * 64 + fm * 16 + (lane >> 4) * 4;
        float4 bv = *(const float4*)(bias + mg);
#pragma unroll
        for (int fn = 0; fn < 2; ++fn) {
            int ng = n0 + wn * 32 + fn * 16 + (lane & 15);
            f32x4 o = acc[fm][fn];
            if (ng >= PIX) { o[0] += bv.x; o[1] += bv.y; o[2] += bv.z; o[3] += bv.w; }
            *(f32x4*)(out + (size_t)ng * CDIM + mg) = o;
        }
    }
}

// ---------------------------------------------------------------------------
// Qm[p][c] = mean over 7x7 window of Qfull pixel cols + Qfull[576] (pos0+bias)
__global__ __launch_bounds__(256) void qmean_k(const float* __restrict__ Qfull, float* __restrict__ Qm) {
    int p = blockIdx.x;
    int i = p / WO, j = p % WO;
    int tid = threadIdx.x;
    float s[8] = {};
    for (int t = 0; t < 49; ++t) {
        int px = (i + t / 7) * WF + (j + t % 7);
        const float* qr = Qfull + (size_t)px * CDIM;
#pragma unroll
        for (int r = 0; r < 8; ++r) s[r] += qr[tid + 256 * r];
    }
    const float* p0 = Qfull + (size_t)PIX * CDIM;
#pragma unroll
    for (int r = 0; r < 8; ++r) {
        int c = tid + 256 * r;
        Qm[(size_t)p * CDIM + c] = s[r] * (1.f / 49.f) + p0[c];
    }
}

// ---------------------------------------------------------------------------
// TW[j][c] = (txt_j/||txt_j||) . out_w[:,c];  cconst[j] = (txt_j/||..||) . out_b
__global__ __launch_bounds__(256) void txtw_k(
    const float* __restrict__ txt, const float* __restrict__ out_w, const float* __restrict__ out_b,
    float* __restrict__ TW, float* __restrict__ cconst)
{
    __shared__ float ts[OUTD];
    __shared__ float red[256], redb[256];
    int j = blockIdx.x, cb = blockIdx.y, tid = threadIdx.x;

    float n2 = 0.f, db = 0.f;
    for (int o = tid; o < OUTD; o += 256) {
        float tv = txt[(size_t)j * OUTD + o];
        ts[o] = tv;
        n2 += tv * tv;
        db += tv * out_b[o];
    }
    red[tid] = n2; redb[tid] = db;
    __syncthreads();
    for (int s = 128; s > 0; s >>= 1) {
        if (tid < s) { red[tid] += red[tid + s]; redb[tid] += redb[tid + s]; }
        __syncthreads();
    }
    float inv = 1.f / sqrtf(red[0]);

    int c = cb * 256 + tid;
    float acc = 0.f;
    for (int o = 0; o < OUTD; ++o)
        acc += ts[o] * out_w[(size_t)o * CDIM + c];
    TW[(size_t)j * CDIM + c] = acc * inv;
    if (cb == 0 && tid == 0) cconst[j] = redb[0] * inv;
}

// ---------------------------------------------------------------------------
// TV[col][h*NTXT+j] = sum_d TW[j][h*64+d] * V[col][h*64+d]
__global__ __launch_bounds__(256) void tv_k(
    const float* __restrict__ TW, const float* __restrict__ Vbuf, float* __restrict__ TV)
{
    __shared__ float TWs[NTXT * HD];
    __shared__ float Vs[8 * HD];
    int cg = blockIdx.x, h = blockIdx.y, tid = threadIdx.x;
    int c0 = cg * 8;

    for (int idx = tid; idx < NTXT * HD; idx += 256) {
        int j = idx / HD, d = idx % HD;
        TWs[idx] = TW[(size_t)j * CDIM + h * HD + d];
    }
    for (int idx = tid; idx < 8 * HD; idx += 256) {
        int c = idx / HD, d = idx % HD;
        int col = c0 + c;
        Vs[idx] = (col < NKV) ? Vbuf[(size_t)col * CDIM + h * HD + d] : 0.f;
    }
    __syncthreads();

    for (int o = tid; o < 8 * NTXT; o += 256) {
        int c = o / NTXT, j = o % NTXT;
        int col = c0 + c;
        if (col >= NKV) continue;
        float acc = 0.f;
#pragma unroll
        for (int d = 0; d < HD; d += 4) {
            float4 tw = *(const float4*)&TWs[j * HD + d];
            float4 vv = *(const float4*)&Vs[c * HD + d];
            acc += tw.x * vv.x + tw.y * vv.y + tw.z * vv.z + tw.w * vv.w;
        }
        TV[(size_t)col * HJ + h * NTXT + j] = acc;
    }
}

// ---------------------------------------------------------------------------
// Per-patch attention + folded text logits + argmax -> bucket
__global__ __launch_bounds__(256) void attn2_k(
    const float* __restrict__ Kbuf, const float* __restrict__ Qm,
    const float* __restrict__ TV, const float* __restrict__ cconst,
    int* __restrict__ bucket)
{
    __shared__ float qs[CDIM];
    __shared__ float scf[NHEAD][NTOK];
    __shared__ float attn[NHEAD][NTOK];
    __shared__ float racc[HJ];
    __shared__ float logit[NTXT];

    int p = blockIdx.x;
    int pi = p / WO, pj = p % WO;
    int tid = threadIdx.x;

#pragma unroll
    for (int r = 0; r < 8; ++r) {
        int c = tid + 256 * r;
        qs[c] = Qm[(size_t)p * CDIM + c];
    }
    __syncthreads();

    for (int pair = tid; pair < NHEAD * 49; pair += 256) {
        int h = pair / 49, t = pair % 49 + 1;
        const float* kb = Kbuf + (size_t)((pi + (t - 1) / 7) * WF + pj + (t - 1) % 7) * CDIM;
        int base = h * HD;
        float dot = 0.f;
#pragma unroll
        for (int d = 0; d < HD; d += 4) {
            float4 qv = *(const float4*)&qs[base + d];
            float4 kv = *(const float4*)&kb[base + d];
            dot += qv.x * kv.x + qv.y * kv.y + qv.z * kv.z + qv.w * kv.w;
        }
        scf[h][t] = dot;
    }
    for (int pair = tid; pair < NHEAD * NTOK; pair += 256) {
        int h = pair / NTOK, t = pair % NTOK;
        const float* kp = Kbuf + (size_t)(PIX + t) * CDIM;
        int base = h * HD;
        float dot = 0.f;
#pragma unroll
        for (int d = 0; d < HD; d += 4) {
            float4 qv = *(const float4*)&qs[base + d];
            float4 kv = *(const float4*)&kp[base + d];
            dot += qv.x * kv.x + qv.y * kv.y + qv.z * kv.z + qv.w * kv.w;
        }
        attn[h][t] = dot;
    }
    __syncthreads();

    if (tid < NHEAD) {
        int h = tid;
        float sF = 0.f;
        for (int t = 1; t < NTOK; ++t) sF += scf[h][t];
        scf[h][0] = sF * (1.f / 49.f);
        float m = -1e30f;
        for (int t = 0; t < NTOK; ++t) {
            float s = (scf[h][t] + attn[h][t]) * 0.125f;
            attn[h][t] = s;
            m = fmaxf(m, s);
        }
        float ssum = 0.f;
        for (int t = 0; t < NTOK; ++t) { float e = expf(attn[h][t] - m); attn[h][t] = e; ssum += e; }
        float invs = 1.f / ssum;
        for (int t = 0; t < NTOK; ++t) attn[h][t] *= invs;
    }
    __syncthreads();

    float lacc[6] = {}, macc[6] = {};
    for (int t = 1; t < NTOK; ++t) {
        const float* TVpix = TV + (size_t)((pi + (t - 1) / 7) * WF + pj + (t - 1) % 7) * HJ;
        const float* TVpos = TV + (size_t)(PIX + t) * HJ;
#pragma unroll
        for (int r = 0; r < 6; ++r) {
            int o = tid + 256 * r;
            if (o < HJ) {
                float a = attn[o / NTXT][t];
                float v1 = TVpix[o];
                lacc[r] += a * (v1 + TVpos[o]);
                macc[r] += v1;
            }
        }
    }
    {
        const float* TVp0 = TV + (size_t)PIX * HJ;
#pragma unroll
        for (int r = 0; r < 6; ++r) {
            int o = tid + 256 * r;
            if (o < HJ) {
                float a0 = attn[o / NTXT][0];
                lacc[r] += a0 * (macc[r] * (1.f / 49.f) + TVp0[o]);
                racc[o] = lacc[r];
            }
        }
    }
    __syncthreads();

    if (tid < NTXT) {
        float s = cconst[tid];
        for (int h = 0; h < NHEAD; ++h) s += racc[h * NTXT + tid];
        logit[tid] = s;
    }
    __syncthreads();
    if (tid == 0) {
        float best = logit[0]; int bi = 0;
        for (int j2 = 1; j2 < NTXT; ++j2)
            if (logit[j2] > best) { best = logit[j2]; bi = j2; }
        int bk = 0;
        const int bounds[5] = {8, 15, 22, 29, 36};
#pragma unroll
        for (int u = 0; u < 5; ++u) bk += (bi >= bounds[u]) ? 1 : 0;
        bucket[p] = bk;
    }
}

// ---------------------------------------------------------------------------
__global__ void votes_k(const int* __restrict__ bucket, float* __restrict__ maxval) {
    __shared__ int bk[NP];
    int tid = threadIdx.x;
    if (tid < NP) bk[tid] = bucket[tid];
    __syncthreads();
    if (tid < PIX) {
        int y = tid / WF, x = tid % WF;
        int cnt[6] = {0, 0, 0, 0, 0, 0};
        int i0 = (y - 6 < 0) ? 0 : y - 6;
        int i1 = (y > HO - 1) ? HO - 1 : y;
        int j0 = (x - 6 < 0) ? 0 : x - 6;
        int j1 = (x > WO - 1) ? WO - 1 : x;
        for (int i = i0; i <= i1; ++i)
            for (int j = j0; j <= j1; ++j)
                cnt[bk[i * WO + j]]++;
        int best = cnt[0], bi = 0;
#pragma unroll
        for (int ch = 1; ch < 6; ++ch)
            if (cnt[ch] > best) { best = cnt[ch]; bi = ch; }
        maxval[tid] = (bi > 0) ? 0.044194173824159216f : 0.f;
    }
}

__global__ void fill_k(const float* __restrict__ maxval, float* __restrict__ out) {
    int idx = blockIdx.x * 256 + threadIdx.x;
    const int HALF = OUTD * PIX;
    if (idx >= 2 * HALF) return;
    out[idx] = (idx < HALF) ? 0.f : maxval[idx % PIX];
}

// ---------------------------------------------------------------------------
extern "C" void kernel_launch(void* const* d_in, const int* in_sizes, int n_in,
                              void* d_out, int out_size, void* d_ws, size_t ws_size,
                              hipStream_t stream) {
    const float* imgf = (const float*)d_in[0];
    const float* txt  = (const float*)d_in[1];
    const float* pos  = (const float*)d_in[2];
    const float* q_w  = (const float*)d_in[3];
    const float* q_b  = (const float*)d_in[4];
    const float* k_w  = (const float*)d_in[5];
    const float* k_b  = (const float*)d_in[6];
    const float* v_w  = (const float*)d_in[7];
    const float* v_b  = (const float*)d_in[8];
    const float* o_w  = (const float*)d_in[9];
    const float* o_b  = (const float*)d_in[10];

    const float* feat1 = imgf + (size_t)1 * CDIM * PIX;   // only batch B-1=1 matters

    float* ws = (float*)d_ws;
    float* Kbuf  = ws;                                   // 640*2048
    float* Vbuf  = Kbuf + (size_t)NROWS * CDIM;
    float* Qfull = Vbuf + (size_t)NROWS * CDIM;
    float* Qm    = Qfull + (size_t)NROWS * CDIM;         // 324*2048
    float* TW    = Qm + (size_t)NP * CDIM;               // 45*2048
    float* cconst = TW + (size_t)NTXT * CDIM;            // 64
    float* TV    = cconst + 64;                          // 626*1440
    int*   bucket = (int*)(TV + (size_t)NKV * HJ);       // 324
    float* maxval = (float*)(bucket + NP);               // 576
    size_t foff = (size_t)(maxval + 576 - ws);
    foff = (foff + 3) & ~(size_t)3;                      // 16B align
    ushort* WhK = (ushort*)(ws + foff);                  // each 2048*2048
    ushort* WlK = WhK + (size_t)CDIM * CDIM;
    ushort* WhV = WlK + (size_t)CDIM * CDIM;
    ushort* WlV = WhV + (size_t)CDIM * CDIM;
    ushort* WhQ = WlV + (size_t)CDIM * CDIM;
    ushort* WlQ = WhQ + (size_t)CDIM * CDIM;
    ushort* Xh  = WlQ + (size_t)CDIM * CDIM;             // 640*2048
    ushort* Xl  = Xh + (size_t)NROWS * CDIM;

    split_w_k<<<dim3(12288), dim3(256), 0, stream>>>(k_w, v_w, q_w, WhK, WlK, WhV, WlV, WhQ, WlQ);
    split_xt_k<<<dim3(9, 32), dim3(256), 0, stream>>>(feat1, Xh, Xl);
    split_pos_k<<<dim3(128), dim3(256), 0, stream>>>(pos, Xh, Xl);
    gemm_bf16_k<<<dim3(16, 10, 3), dim3(256), 0, stream>>>(WhK, WlK, WhV, WlV, WhQ, WlQ,
                                                           Xh, Xl, k_b, v_b, q_b, Kbuf, Vbuf, Qfull);
    qmean_k<<<dim3(NP), dim3(256), 0, stream>>>(Qfull, Qm);
    txtw_k<<<dim3(NTXT, 8), dim3(256), 0, stream>>>(txt, o_w, o_b, TW, cconst);
    tv_k<<<dim3(79, 32), dim3(256), 0, stream>>>(TW, Vbuf, TV);
    attn2_k<<<dim3(NP), dim3(256), 0, stream>>>(Kbuf, Qm, TV, cconst, bucket);
    votes_k<<<dim3(1), dim3(576), 0, stream>>>(bucket, maxval);
    fill_k<<<dim3(2304), dim3(256), 0, stream>>>(maxval, (float*)d_out);
}

// Round 5
// 263.411 us; speedup vs baseline: 2.2846x; 1.2489x over previous
//
#include <hip/hip_runtime.h>
#include <math.h>

#define CDIM 2048
#define HF 24
#define WF 24
#define PIX 576
#define HO 18
#define WO 18
#define NP 324
#define NHEAD 32
#define HD 64
#define NTOK 50
#define NTXT 45
#define OUTD 512
#define NKV 626
#define HJ (NHEAD * NTXT)   // 1440
#define NROWS 640           // padded B rows: 576 pixels + 50 pos + 14 zero

typedef __attribute__((ext_vector_type(8))) short short8;
typedef __attribute__((ext_vector_type(4))) float f32x4;
typedef __attribute__((address_space(1))) const void as1c_void;
typedef __attribute__((address_space(3))) void as3_void;

__device__ inline unsigned bf16rn(float x) {
    unsigned u = __float_as_uint(x);
    return (u + 0x7FFFu + ((u >> 16) & 1u)) >> 16;
}
__device__ inline float bf16tof(unsigned h) { return __uint_as_float(h << 16); }

// ---------------------------------------------------------------------------
// Split the 3 weight matrices into hi/lo bf16 (same [m][k] layout).
__global__ void split_w_k(const float* __restrict__ kw, const float* __restrict__ vw, const float* __restrict__ qw,
                          ushort* __restrict__ WhK, ushort* __restrict__ WlK,
                          ushort* __restrict__ WhV, ushort* __restrict__ WlV,
                          ushort* __restrict__ WhQ, ushort* __restrict__ WlQ) {
    int g = blockIdx.x * 256 + threadIdx.x;      // 3 * 1048576 threads, 4 elems each
    int sel = g >> 20;
    int off = (g & 1048575) * 4;
    const float* src = sel == 0 ? kw : sel == 1 ? vw : qw;
    ushort* dh = sel == 0 ? WhK : sel == 1 ? WhV : WhQ;
    ushort* dl = sel == 0 ? WlK : sel == 1 ? WlV : WlQ;
    float4 v = *(const float4*)(src + off);
    float xs[4] = {v.x, v.y, v.z, v.w};
    ushort h[4], l[4];
#pragma unroll
    for (int i = 0; i < 4; ++i) {
        unsigned hh = bf16rn(xs[i]);
        h[i] = (ushort)hh;
        l[i] = (ushort)bf16rn(xs[i] - bf16tof(hh));
    }
    *(ushort4*)(dh + off) = make_ushort4(h[0], h[1], h[2], h[3]);
    *(ushort4*)(dl + off) = make_ushort4(l[0], l[1], l[2], l[3]);
}

// ---------------------------------------------------------------------------
// Transpose+split feat1 [2048][576] f32 -> Xh/Xl [640][2048] bf16 rows 0..575.
__global__ __launch_bounds__(256) void split_xt_k(const float* __restrict__ feat1,
                                                  ushort* __restrict__ Xh, ushort* __restrict__ Xl) {
    __shared__ float tile[64][65];
    int n0 = blockIdx.x * 64, c0 = blockIdx.y * 64, tid = threadIdx.x;
#pragma unroll
    for (int i = 0; i < 16; ++i) {
        int idx = tid + i * 256;
        int cc = idx >> 6, nn = idx & 63;
        tile[cc][nn] = feat1[(size_t)(c0 + cc) * PIX + n0 + nn];
    }
    __syncthreads();
#pragma unroll
    for (int i = 0; i < 16; ++i) {
        int idx = tid + i * 256;
        int nn = idx >> 6, cc = idx & 63;
        float x = tile[cc][nn];
        unsigned hh = bf16rn(x);
        Xh[(size_t)(n0 + nn) * CDIM + c0 + cc] = (ushort)hh;
        Xl[(size_t)(n0 + nn) * CDIM + c0 + cc] = (ushort)bf16rn(x - bf16tof(hh));
    }
}

// ---------------------------------------------------------------------------
// Rows 576..639 of Xh/Xl: pos tokens (split) for r<50, zeros for pad rows.
__global__ void split_pos_k(const float* __restrict__ pos,
                            ushort* __restrict__ Xh, ushort* __restrict__ Xl) {
    int g = blockIdx.x * 256 + threadIdx.x;     // 32768 threads, 4 elems each
    int r = g >> 9;                              // 0..63
    int c = (g & 511) * 4;
    float4 v = make_float4(0.f, 0.f, 0.f, 0.f);
    if (r < 50) v = *(const float4*)(pos + (size_t)r * CDIM + c);
    float xs[4] = {v.x, v.y, v.z, v.w};
    ushort h[4], l[4];
#pragma unroll
    for (int i = 0; i < 4; ++i) {
        unsigned hh = bf16rn(xs[i]);
        h[i] = (ushort)hh;
        l[i] = (ushort)bf16rn(xs[i] - bf16tof(hh));
    }
    size_t o = (size_t)(576 + r) * CDIM + c;
    *(ushort4*)(Xh + o) = make_ushort4(h[0], h[1], h[2], h[3]);
    *(ushort4*)(Xl + o) = make_ushort4(l[0], l[1], l[2], l[3]);
}

// ---------------------------------------------------------------------------
// Split-bf16 MFMA GEMM, 2-phase async pipeline (unchanged from round 4).
#define BUFB 24576
__global__ __launch_bounds__(256, 2) void gemm_bf16_k(
    const ushort* __restrict__ WhK, const ushort* __restrict__ WlK,
    const ushort* __restrict__ WhV, const ushort* __restrict__ WlV,
    const ushort* __restrict__ WhQ, const ushort* __restrict__ WlQ,
    const ushort* __restrict__ Xh, const ushort* __restrict__ Xl,
    const float* __restrict__ k_b, const float* __restrict__ v_b, const float* __restrict__ q_b,
    float* __restrict__ Kbuf, float* __restrict__ Vbuf, float* __restrict__ Qfull)
{
    __shared__ char smem[2 * BUFB];
    int z = blockIdx.z;
    const ushort* Wh = z == 0 ? WhK : z == 1 ? WhV : WhQ;
    const ushort* Wl = z == 0 ? WlK : z == 1 ? WlV : WlQ;
    const float* bias = z == 0 ? k_b : z == 1 ? v_b : q_b;
    float* out = z == 0 ? Kbuf : z == 1 ? Vbuf : Qfull;
    int m0 = blockIdx.x * 128, n0 = blockIdx.y * 64;

    int tid = threadIdx.x, wid = tid >> 6, lane = tid & 63;
    int lrow = lane & 15, lk = lane >> 4;
    int wm = wid >> 1, wn = wid & 1;

    const char* gsrc[6];
    int ldsoff[6];
#pragma unroll
    for (int i = 0; i < 6; ++i) {
        int g = wid * 6 + i;
        const ushort* src; int row; int off;
        if (g < 8)       { src = Wh; row = m0 + g * 16 + lrow;        off = g * 1024; }
        else if (g < 16) { src = Wl; row = m0 + (g - 8) * 16 + lrow;  off = 8192 + (g - 8) * 1024; }
        else if (g < 20) { src = Xh; row = n0 + (g - 16) * 16 + lrow; off = 16384 + (g - 16) * 1024; }
        else             { src = Xl; row = n0 + (g - 20) * 16 + lrow; off = 20480 + (g - 20) * 1024; }
        gsrc[i] = (const char*)(src + (size_t)row * CDIM + lk * 8);
        ldsoff[i] = off;
    }

    f32x4 acc[4][2];
#pragma unroll
    for (int a = 0; a < 4; ++a)
#pragma unroll
        for (int b = 0; b < 2; ++b) acc[a][b] = (f32x4)0.f;

#pragma unroll
    for (int i = 0; i < 6; ++i)
        __builtin_amdgcn_global_load_lds((as1c_void*)(gsrc[i]),
                                         (as3_void*)(smem + ldsoff[i]), 16, 0, 0);
    __syncthreads();

    int cur = 0;
    for (int t = 0; t < 64; ++t) {
        char* rbuf = smem + cur * BUFB;
        char* wbuf = smem + (cur ^ 1) * BUFB;
        if (t < 63) {
#pragma unroll
            for (int i = 0; i < 6; ++i)
                __builtin_amdgcn_global_load_lds((as1c_void*)(gsrc[i] + (size_t)(t + 1) * 64),
                                                 (as3_void*)(wbuf + ldsoff[i]), 16, 0, 0);
        }

        short8 ah[4], al[4];
#pragma unroll
        for (int fm = 0; fm < 4; ++fm) {
            int s = wm * 4 + fm;
            ah[fm] = *(const short8*)(rbuf + s * 1024 + lane * 16);
            al[fm] = *(const short8*)(rbuf + 8192 + s * 1024 + lane * 16);
        }
        short8 bh[2], bl[2];
#pragma unroll
        for (int fn = 0; fn < 2; ++fn) {
            int s = wn * 2 + fn;
            bh[fn] = *(const short8*)(rbuf + 16384 + s * 1024 + lane * 16);
            bl[fn] = *(const short8*)(rbuf + 20480 + s * 1024 + lane * 16);
        }
#pragma unroll
        for (int fn = 0; fn < 2; ++fn)
#pragma unroll
            for (int fm = 0; fm < 4; ++fm) {
                acc[fm][fn] = __builtin_amdgcn_mfma_f32_16x16x32_bf16(ah[fm], bh[fn], acc[fm][fn], 0, 0, 0);
                acc[fm][fn] = __builtin_amdgcn_mfma_f32_16x16x32_bf16(ah[fm], bl[fn], acc[fm][fn], 0, 0, 0);
                acc[fm][fn] = __builtin_amdgcn_mfma_f32_16x16x32_bf16(al[fm], bh[fn], acc[fm][fn], 0, 0, 0);
            }
        __syncthreads();
        cur ^= 1;
    }

#pragma unroll
    for (int fm = 0; fm < 4; ++fm) {
        int mg = m0 + wm * 64 + fm * 16 + (lane >> 4) * 4;
        float4 bv = *(const float4*)(bias + mg);
#pragma unroll
        for (int fn = 0; fn < 2; ++fn) {
            int ng = n0 + wn * 32 + fn * 16 + (lane & 15);
            f32x4 o = acc[fm][fn];
            if (ng >= PIX) { o[0] += bv.x; o[1] += bv.y; o[2] += bv.z; o[3] += bv.w; }
            *(f32x4*)(out + (size_t)ng * CDIM + mg) = o;
        }
    }
}

// ---------------------------------------------------------------------------
// Qm[p][c] = mean over 7x7 window of Qfull pixel cols + Qfull[576] (pos0+bias)
// grid (NP, 2): c-halves; one float4/row/thread.
__global__ __launch_bounds__(256) void qmean_k(const float* __restrict__ Qfull, float* __restrict__ Qm) {
    int p = blockIdx.x;
    int i = p / WO, j = p % WO;
    int c = blockIdx.y * 1024 + threadIdx.x * 4;
    float4 s = make_float4(0.f, 0.f, 0.f, 0.f);
#pragma unroll 7
    for (int t = 0; t < 49; ++t) {
        int px = (i + t / 7) * WF + (j + t % 7);
        float4 v = *(const float4*)(Qfull + (size_t)px * CDIM + c);
        s.x += v.x; s.y += v.y; s.z += v.z; s.w += v.w;
    }
    float4 p0 = *(const float4*)(Qfull + (size_t)PIX * CDIM + c);
    float4 r;
    r.x = s.x * (1.f / 49.f) + p0.x;
    r.y = s.y * (1.f / 49.f) + p0.y;
    r.z = s.z * (1.f / 49.f) + p0.z;
    r.w = s.w * (1.f / 49.f) + p0.w;
    *(float4*)(Qm + (size_t)p * CDIM + c) = r;
}

// ---------------------------------------------------------------------------
// TW[j][c] = (txt_j/||txt_j||) . out_w[:,c];  cconst[j] = (txt_j/||..||) . out_b
__global__ __launch_bounds__(256) void txtw_k(
    const float* __restrict__ txt, const float* __restrict__ out_w, const float* __restrict__ out_b,
    float* __restrict__ TW, float* __restrict__ cconst)
{
    __shared__ float ts[OUTD];
    __shared__ float red[256], redb[256];
    int j = blockIdx.x, cb = blockIdx.y, tid = threadIdx.x;

    float n2 = 0.f, db = 0.f;
    for (int o = tid; o < OUTD; o += 256) {
        float tv = txt[(size_t)j * OUTD + o];
        ts[o] = tv;
        n2 += tv * tv;
        db += tv * out_b[o];
    }
    red[tid] = n2; redb[tid] = db;
    __syncthreads();
    for (int s = 128; s > 0; s >>= 1) {
        if (tid < s) { red[tid] += red[tid + s]; redb[tid] += redb[tid + s]; }
        __syncthreads();
    }
    float inv = 1.f / sqrtf(red[0]);

    int c = cb * 256 + tid;
    float acc = 0.f;
    for (int o = 0; o < OUTD; ++o)
        acc += ts[o] * out_w[(size_t)o * CDIM + c];
    TW[(size_t)j * CDIM + c] = acc * inv;
    if (cb == 0 && tid == 0) cconst[j] = redb[0] * inv;
}

// ---------------------------------------------------------------------------
// TV[col][h*NTXT+j] = sum_d TW[j][h*64+d] * V[col][h*64+d]
__global__ __launch_bounds__(256) void tv_k(
    const float* __restrict__ TW, const float* __restrict__ Vbuf, float* __restrict__ TV)
{
    __shared__ float TWs[NTXT * HD];
    __shared__ float Vs[8 * HD];
    int cg = blockIdx.x, h = blockIdx.y, tid = threadIdx.x;
    int c0 = cg * 8;

    for (int idx = tid; idx < NTXT * HD; idx += 256) {
        int j = idx / HD, d = idx % HD;
        TWs[idx] = TW[(size_t)j * CDIM + h * HD + d];
    }
    for (int idx = tid; idx < 8 * HD; idx += 256) {
        int c = idx / HD, d = idx % HD;
        int col = c0 + c;
        Vs[idx] = (col < NKV) ? Vbuf[(size_t)col * CDIM + h * HD + d] : 0.f;
    }
    __syncthreads();

    for (int o = tid; o < 8 * NTXT; o += 256) {
        int c = o / NTXT, j = o % NTXT;
        int col = c0 + c;
        if (col >= NKV) continue;
        float acc = 0.f;
#pragma unroll
        for (int d = 0; d < HD; d += 4) {
            float4 tw = *(const float4*)&TWs[j * HD + d];
            float4 vv = *(const float4*)&Vs[c * HD + d];
            acc += tw.x * vv.x + tw.y * vv.y + tw.z * vv.z + tw.w * vv.w;
        }
        TV[(size_t)col * HJ + h * NTXT + j] = acc;
    }
}

// ---------------------------------------------------------------------------
// Fused per-(patch, 8-head-slice) scores + softmax + folded pooling.
// grid (NP, 4), block 384. Writes pooledHJ[p][o] for o in [s*360, s*360+360).
__global__ __launch_bounds__(384) void attn_fused_k(
    const float* __restrict__ Kbuf, const float* __restrict__ Qm,
    const float* __restrict__ TV, float* __restrict__ pooledHJ)
{
    __shared__ float qs[8 * HD];       // 512: q slice for 8 heads
    __shared__ float scf[8][NTOK];     // feature scores -> probs after softmax
    __shared__ float scp[8][NTOK];     // pos scores -> combined scores
    __shared__ int win[49];            // window pixel indices

    int p = blockIdx.x, s = blockIdx.y;
    int h0 = s * 8;
    int pi = p / WO, pj = p % WO;
    int tid = threadIdx.x;

    if (tid < 128)
        *(float4*)&qs[tid * 4] = *(const float4*)(Qm + (size_t)p * CDIM + h0 * HD + tid * 4);
    if (tid < 49)
        win[tid] = (pi + tid / 7) * WF + (pj + tid % 7);
    __syncthreads();

    // feature scores: 8 heads x 49 tokens
    for (int pair = tid; pair < 8 * 49; pair += 384) {
        int h = pair / 49, t = pair % 49 + 1;
        const float* kb = Kbuf + (size_t)win[t - 1] * CDIM + (h0 + h) * HD;
        float dot = 0.f;
#pragma unroll
        for (int d = 0; d < HD; d += 4) {
            float4 qv = *(const float4*)&qs[h * HD + d];
            float4 kv = *(const float4*)&kb[d];
            dot += qv.x * kv.x + qv.y * kv.y + qv.z * kv.z + qv.w * kv.w;
        }
        scf[h][t] = dot;
    }
    // pos scores: 8 heads x 50 tokens
    for (int pair = tid; pair < 8 * NTOK; pair += 384) {
        int h = pair / NTOK, t = pair % NTOK;
        const float* kp = Kbuf + (size_t)(PIX + t) * CDIM + (h0 + h) * HD;
        float dot = 0.f;
#pragma unroll
        for (int d = 0; d < HD; d += 4) {
            float4 qv = *(const float4*)&qs[h * HD + d];
            float4 kv = *(const float4*)&kp[d];
            dot += qv.x * kv.x + qv.y * kv.y + qv.z * kv.z + qv.w * kv.w;
        }
        scp[h][t] = dot;
    }
    __syncthreads();

    // softmax per head; mean-token feature part = mean of scf[1..49]
    if (tid < 8) {
        int h = tid;
        float sF = 0.f;
        for (int t = 1; t < NTOK; ++t) sF += scf[h][t];
        scf[h][0] = sF * (1.f / 49.f);
        float m = -1e30f;
        for (int t = 0; t < NTOK; ++t) {
            float sc = (scf[h][t] + scp[h][t]) * 0.125f;
            scp[h][t] = sc;
            m = fmaxf(m, sc);
        }
        float ssum = 0.f;
        for (int t = 0; t < NTOK; ++t) { float e = expf(scp[h][t] - m); scf[h][t] = e; ssum += e; }
        float inv = 1.f / ssum;
        for (int t = 0; t < NTOK; ++t) scf[h][t] *= inv;
    }
    __syncthreads();

    // folded pooling for this slice's o-window (contiguous, coalesced)
    if (tid < 360) {
        int o = s * 360 + tid;
        int hloc = tid / 45;
        const float* apr = &scf[hloc][0];
        float lacc = 0.f, macc = 0.f;
#pragma unroll 7
        for (int t = 1; t < NTOK; ++t) {
            float a = apr[t];
            float v1 = TV[(size_t)win[t - 1] * HJ + o];
            float v2 = TV[(size_t)(PIX + t) * HJ + o];
            lacc += a * (v1 + v2);
            macc += v1;
        }
        float a0 = apr[0];
        lacc += a0 * (macc * (1.f / 49.f) + TV[(size_t)PIX * HJ + o]);
        pooledHJ[(size_t)p * HJ + o] = lacc;
    }
}

// ---------------------------------------------------------------------------
// finish: reduce pooledHJ over heads, add cconst, argmax -> bucket
__global__ __launch_bounds__(64) void finish_k(const float* __restrict__ pooledHJ,
                                               const float* __restrict__ cconst,
                                               int* __restrict__ bucket) {
    __shared__ float lg[NTXT];
    int p = blockIdx.x, lane = threadIdx.x;
    if (lane < NTXT) {
        float s = cconst[lane];
        const float* row = pooledHJ + (size_t)p * HJ;
#pragma unroll 8
        for (int h = 0; h < NHEAD; ++h) s += row[h * NTXT + lane];
        lg[lane] = s;
    }
    __syncthreads();
    if (lane == 0) {
        float best = lg[0]; int bi = 0;
        for (int j2 = 1; j2 < NTXT; ++j2)
            if (lg[j2] > best) { best = lg[j2]; bi = j2; }
        int bk = 0;
        const int bounds[5] = {8, 15, 22, 29, 36};
#pragma unroll
        for (int u = 0; u < 5; ++u) bk += (bi >= bounds[u]) ? 1 : 0;
        bucket[p] = bk;
    }
}

// ---------------------------------------------------------------------------
__global__ void votes_k(const int* __restrict__ bucket, float* __restrict__ maxval) {
    __shared__ int bk[NP];
    int tid = threadIdx.x;
    if (tid < NP) bk[tid] = bucket[tid];
    __syncthreads();
    if (tid < PIX) {
        int y = tid / WF, x = tid % WF;
        int cnt[6] = {0, 0, 0, 0, 0, 0};
        int i0 = (y - 6 < 0) ? 0 : y - 6;
        int i1 = (y > HO - 1) ? HO - 1 : y;
        int j0 = (x - 6 < 0) ? 0 : x - 6;
        int j1 = (x > WO - 1) ? WO - 1 : x;
        for (int i = i0; i <= i1; ++i)
            for (int j = j0; j <= j1; ++j)
                cnt[bk[i * WO + j]]++;
        int best = cnt[0], bi = 0;
#pragma unroll
        for (int ch = 1; ch < 6; ++ch)
            if (cnt[ch] > best) { best = cnt[ch]; bi = ch; }
        maxval[tid] = (bi > 0) ? 0.044194173824159216f : 0.f;
    }
}

__global__ void fill_k(const float* __restrict__ maxval, float* __restrict__ out) {
    int idx = blockIdx.x * 256 + threadIdx.x;
    const int HALF = OUTD * PIX;
    if (idx >= 2 * HALF) return;
    out[idx] = (idx < HALF) ? 0.f : maxval[idx % PIX];
}

// ---------------------------------------------------------------------------
extern "C" void kernel_launch(void* const* d_in, const int* in_sizes, int n_in,
                              void* d_out, int out_size, void* d_ws, size_t ws_size,
                              hipStream_t stream) {
    const float* imgf = (const float*)d_in[0];
    const float* txt  = (const float*)d_in[1];
    const float* pos  = (const float*)d_in[2];
    const float* q_w  = (const float*)d_in[3];
    const float* q_b  = (const float*)d_in[4];
    const float* k_w  = (const float*)d_in[5];
    const float* k_b  = (const float*)d_in[6];
    const float* v_w  = (const float*)d_in[7];
    const float* v_b  = (const float*)d_in[8];
    const float* o_w  = (const float*)d_in[9];
    const float* o_b  = (const float*)d_in[10];

    const float* feat1 = imgf + (size_t)1 * CDIM * PIX;   // only batch B-1=1 matters

    float* ws = (float*)d_ws;
    float* Kbuf  = ws;                                   // 640*2048
    float* Vbuf  = Kbuf + (size_t)NROWS * CDIM;
    float* Qfull = Vbuf + (size_t)NROWS * CDIM;
    float* Qm    = Qfull + (size_t)NROWS * CDIM;         // 324*2048
    float* TW    = Qm + (size_t)NP * CDIM;               // 45*2048
    float* cconst = TW + (size_t)NTXT * CDIM;            // 64
    float* TV    = cconst + 64;                          // 626*1440
    float* pooledHJ = TV + (size_t)NKV * HJ;             // 324*1440
    int*   bucket = (int*)(pooledHJ + (size_t)NP * HJ);  // 324
    float* maxval = (float*)(bucket + NP);               // 576
    size_t foff = (size_t)(maxval + 576 - ws);
    foff = (foff + 3) & ~(size_t)3;                      // 16B align
    ushort* WhK = (ushort*)(ws + foff);                  // each 2048*2048
    ushort* WlK = WhK + (size_t)CDIM * CDIM;
    ushort* WhV = WlK + (size_t)CDIM * CDIM;
    ushort* WlV = WhV + (size_t)CDIM * CDIM;
    ushort* WhQ = WlV + (size_t)CDIM * CDIM;
    ushort* WlQ = WhQ + (size_t)CDIM * CDIM;
    ushort* Xh  = WlQ + (size_t)CDIM * CDIM;             // 640*2048
    ushort* Xl  = Xh + (size_t)NROWS * CDIM;

    split_w_k<<<dim3(12288), dim3(256), 0, stream>>>(k_w, v_w, q_w, WhK, WlK, WhV, WlV, WhQ, WlQ);
    split_xt_k<<<dim3(9, 32), dim3(256), 0, stream>>>(feat1, Xh, Xl);
    split_pos_k<<<dim3(128), dim3(256), 0, stream>>>(pos, Xh, Xl);
    gemm_bf16_k<<<dim3(16, 10, 3), dim3(256), 0, stream>>>(WhK, WlK, WhV, WlV, WhQ, WlQ,
                                                           Xh, Xl, k_b, v_b, q_b, Kbuf, Vbuf, Qfull);
    qmean_k<<<dim3(NP, 2), dim3(256), 0, stream>>>(Qfull, Qm);
    txtw_k<<<dim3(NTXT, 8), dim3(256), 0, stream>>>(txt, o_w, o_b, TW, cconst);
    tv_k<<<dim3(79, 32), dim3(256), 0, stream>>>(TW, Vbuf, TV);
    attn_fused_k<<<dim3(NP, 4), dim3(384), 0, stream>>>(Kbuf, Qm, TV, pooledHJ);
    finish_k<<<dim3(NP), dim3(64), 0, stream>>>(pooledHJ, cconst, bucket);
    votes_k<<<dim3(1), dim3(576), 0, stream>>>(bucket, maxval);
    fill_k<<<dim3(2304), dim3(256), 0, stream>>>(maxval, (float*)d_out);
}